// Round 9
// baseline (896.999 us; speedup 1.0000x reference)
//
#include <hip/hip_runtime.h>
#include <math.h>
#include <stdint.h>

#define B_ 32
#define S_ 2048
#define D_ 1024
#define H_ 1024
#define NEGV -1000000000000.0f

typedef __attribute__((ext_vector_type(8))) short bf16x8;
typedef __attribute__((ext_vector_type(4))) float f32x4;

static __device__ __forceinline__ unsigned short f2bf(float x) {
    union { float f; unsigned u; } v; v.f = x;
    unsigned r = v.u + 0x7FFF + ((v.u >> 16) & 1);
    return (unsigned short)(r >> 16);
}
static __device__ __forceinline__ float bf2f(unsigned short h) {
    union { float f; unsigned u; } v; v.u = ((unsigned)h) << 16; return v.f;
}
static __device__ __forceinline__ float tanh_fast(float x) {
    float e = __expf(2.f * x);
    return 1.f - 2.f / (e + 1.f);
}
static __device__ __forceinline__ void gl_lds16(unsigned short* lds, const unsigned short* g) {
    __builtin_amdgcn_global_load_lds(
        (const __attribute__((address_space(1))) unsigned int*)(const void*)g,
        (__attribute__((address_space(3))) unsigned int*)(void*)lds,
        16, 0, 0);
}

// ---------- split We = W[:, D:] into bf16 hi/lo, LINEAR row-major [H][D] ----------
__global__ __launch_bounds__(256) void k_splitW_lin(const float* __restrict__ W,
                                                    unsigned short* __restrict__ hi,
                                                    unsigned short* __restrict__ lo) {
    int idx = blockIdx.x * 256 + threadIdx.x;
    int h = idx >> 7, kc = idx & 127;
    const float* src = W + (size_t)h * (2 * D_) + D_ + kc * 8;
    float4 a = *(const float4*)src;
    float4 c = *(const float4*)(src + 4);
    float v[8] = {a.x, a.y, a.z, a.w, c.x, c.y, c.z, c.w};
    unsigned short th[8], tl[8];
#pragma unroll
    for (int j = 0; j < 8; ++j) {
        th[j] = f2bf(v[j]);
        tl[j] = f2bf(v[j] - bf2f(th[j]));
    }
    uint4 hw, lw;
    hw.x = th[0] | ((unsigned)th[1] << 16); hw.y = th[2] | ((unsigned)th[3] << 16);
    hw.z = th[4] | ((unsigned)th[5] << 16); hw.w = th[6] | ((unsigned)th[7] << 16);
    lw.x = tl[0] | ((unsigned)tl[1] << 16); lw.y = tl[2] | ((unsigned)tl[3] << 16);
    lw.z = tl[4] | ((unsigned)tl[5] << 16); lw.w = tl[6] | ((unsigned)tl[7] << 16);
    *(uint4*)(hi + (size_t)h * D_ + kc * 8) = hw;
    *(uint4*)(lo + (size_t)h * D_ + kc * 8) = lw;
}

// ---------- split enc into bf16 hi/lo, LINEAR ----------
__global__ __launch_bounds__(256) void k_split_enc(const float* __restrict__ enc,
                                                   unsigned short* __restrict__ hi,
                                                   unsigned short* __restrict__ lo) {
    size_t base = ((size_t)blockIdx.x * 256 + threadIdx.x) * 8;
    float4 a = *(const float4*)(enc + base);
    float4 c = *(const float4*)(enc + base + 4);
    float v[8] = {a.x, a.y, a.z, a.w, c.x, c.y, c.z, c.w};
    unsigned short th[8], tl[8];
#pragma unroll
    for (int j = 0; j < 8; ++j) {
        th[j] = f2bf(v[j]);
        tl[j] = f2bf(v[j] - bf2f(th[j]));
    }
    uint4 hw, lw;
    hw.x = th[0] | ((unsigned)th[1] << 16); hw.y = th[2] | ((unsigned)th[3] << 16);
    hw.z = th[4] | ((unsigned)th[5] << 16); hw.w = th[6] | ((unsigned)th[7] << 16);
    lw.x = tl[0] | ((unsigned)tl[1] << 16); lw.y = tl[2] | ((unsigned)tl[3] << 16);
    lw.z = tl[4] | ((unsigned)tl[5] << 16); lw.w = tl[6] | ((unsigned)tl[7] << 16);
    *(uint4*)(hi + base) = hw;
    *(uint4*)(lo + base) = lw;
}

// ---------- h_part ----------
__global__ __launch_bounds__(256) void k_hpart(const float* __restrict__ ls,
                                               const float* __restrict__ W,
                                               float* __restrict__ hp) {
    int bh = blockIdx.x * 256 + threadIdx.x;
    int b = bh >> 10, h = bh & 1023;
    const float* lsr = ls + b * D_;
    const float* wr  = W + (size_t)h * (2 * D_);
    float acc = 0.f;
#pragma unroll 4
    for (int d = 0; d < D_; d += 4) {
        float4 a = *(const float4*)(lsr + d);
        float4 w = *(const float4*)(wr + d);
        acc += a.x * w.x + a.y * w.y + a.z * w.z + a.w * w.w;
    }
    hp[bh] = acc;
}

// ---------- main GEMM: 128x128 tile, BK=64, double-buffered, 2 blocks/CU ----------
// K'' = 3072 = 48 K-tiles: tile t -> (gd = t/3, plane p = t%3)
//   A plane: p<2 ? ench : encl ; B plane: p==1 ? Wlo : Whi
// r6 schedule (sound): issue all 8 gl_lds for t+1 at iteration start into slot
// nxt, compute t from cur, one __syncthreads per iteration. 64KB LDS -> 2
// blocks/CU: one block's barrier drain overlaps the other block's MFMA (m114).
// LDS layout per slot (conflict-free + gl_lds-linear, linear globals):
//   [8 rowgroups][8 kchunks][16 rows] x 8 shorts ; addr = rg*1024 + kc*128 + r*8
__global__ __launch_bounds__(256, 2) void k_scores_128(
    const unsigned short* __restrict__ ench, const unsigned short* __restrict__ encl,
    const unsigned short* __restrict__ Whi,  const unsigned short* __restrict__ Wlo,
    const float* __restrict__ hp, const float* __restrict__ bias,
    const float* __restrict__ V, float* __restrict__ spart)
{
    __shared__ __align__(16) unsigned short smem[32768];   // 64 KB
    unsigned short* smemA = smem;             // 2 slots x 8192 shorts
    unsigned short* smemB = smem + 16384;     // 2 slots x 8192 shorts

    const int tid  = threadIdx.x;
    const int lane = tid & 63, wid = tid >> 6;        // 4 waves
    const int wm = wid >> 1, wn = wid & 1;            // 2 x 2, wave tile 64x64
    const int l15 = lane & 15, lhi = lane >> 4;

    // XCD swizzle: nwg = 4096; 512 per XCD; 8 consecutive = one m-tile's n-tiles
    const int bid  = blockIdx.x;
    const int wgid = (bid & 7) * 512 + (bid >> 3);
    const int mt = wgid >> 3, nt = wgid & 7;
    const int m0 = mt * 128;
    const int n0 = nt * 128;
    const int b  = m0 >> 11;

    // staging: wave wid covers rows [wid*32, wid*32+32) of both A and B tiles.
    // issue j (0..3): lane l -> row (j>>1)*16 + (l&15), kchunk (j&1)*4 + (l>>4)
    const size_t a_base = (size_t)(m0 + wid * 32 + l15) * D_ + lhi * 8;
    const size_t b_base = (size_t)(n0 + wid * 32 + l15) * D_ + lhi * 8;
    const int ldsw = wid * 2048;              // 2 rowgroups per wave

    f32x4 acc[4][4];
#pragma unroll
    for (int i = 0; i < 4; ++i)
#pragma unroll
        for (int j = 0; j < 4; ++j)
            acc[i][j] = (f32x4){0.f, 0.f, 0.f, 0.f};

#define STAGE(SLOT, PA, PB, KOFS) do {                                              \
    _Pragma("unroll")                                                               \
    for (int j_ = 0; j_ < 4; ++j_)                                                  \
        gl_lds16(&smemA[(SLOT) * 8192 + ldsw + j_ * 512],                           \
                 (PA) + a_base + (size_t)(j_ >> 1) * 16 * D_ + (j_ & 1) * 32 + (KOFS)); \
    _Pragma("unroll")                                                               \
    for (int j_ = 0; j_ < 4; ++j_)                                                  \
        gl_lds16(&smemB[(SLOT) * 8192 + ldsw + j_ * 512],                           \
                 (PB) + b_base + (size_t)(j_ >> 1) * 16 * D_ + (j_ & 1) * 32 + (KOFS)); \
} while (0)

#define LDA(AR, SLOT, KS) do {                                                      \
    _Pragma("unroll")                                                               \
    for (int fi_ = 0; fi_ < 4; ++fi_)                                               \
        AR[fi_] = *(const bf16x8*)&smemA[(SLOT) * 8192 +                            \
            (wm * 4 + fi_) * 1024 + ((KS) * 4 + lhi) * 128 + l15 * 8];              \
} while (0)
#define LDB(BR, SLOT, KS) do {                                                      \
    _Pragma("unroll")                                                               \
    for (int fi_ = 0; fi_ < 4; ++fi_)                                               \
        BR[fi_] = *(const bf16x8*)&smemB[(SLOT) * 8192 +                            \
            (wn * 4 + fi_) * 1024 + ((KS) * 4 + lhi) * 128 + l15 * 8];              \
} while (0)
#define MFMA16(AR, BR) do {                                                         \
    __builtin_amdgcn_s_setprio(1);                                                  \
    _Pragma("unroll")                                                               \
    for (int fi_ = 0; fi_ < 4; ++fi_)                                               \
    _Pragma("unroll")                                                               \
        for (int fj_ = 0; fj_ < 4; ++fj_)                                           \
            acc[fi_][fj_] = __builtin_amdgcn_mfma_f32_16x16x32_bf16(                \
                AR[fi_], BR[fj_], acc[fi_][fj_], 0, 0, 0);                          \
    __builtin_amdgcn_s_setprio(0);                                                  \
} while (0)

    // ---- prologue: stage tile 0 (gd0, p0: A=hi, B=hi) into slot 0
    STAGE(0, ench, Whi, 0);
    __syncthreads();

    bf16x8 a[4], bk[4];
#pragma unroll 1
    for (int t = 0; t < 48; ++t) {
        const int cur = t & 1, nxt = cur ^ 1;

        if (t < 47) {
            const int tn   = t + 1;
            const int gd_n = tn / 3;
            const int p_n  = tn - gd_n * 3;
            const unsigned short* pa = (p_n < 2) ? ench : encl;
            const unsigned short* pb = (p_n == 1) ? Wlo : Whi;
            STAGE(nxt, pa, pb, gd_n * 64);
        }

#pragma unroll
        for (int ks = 0; ks < 2; ++ks) {
            LDB(bk, cur, ks);
            LDA(a, cur, ks);
            MFMA16(a, bk);
        }

        __syncthreads();   // t+1 loads landed; reads of cur done -> slot reuse safe
    }

    // ---- epilogue: tanh + V-weighted reduce
    float hb[4], vv[4];
#pragma unroll
    for (int fn = 0; fn < 4; ++fn) {
        int h = n0 + wn * 64 + fn * 16 + l15;
        hb[fn] = hp[b * H_ + h] + bias[h];
        vv[fn] = V[h];
    }
    float* s_red = (float*)smem;              // 256 floats, safe after final barrier
#pragma unroll
    for (int fm = 0; fm < 4; ++fm)
#pragma unroll
        for (int rg = 0; rg < 4; ++rg) {
            float rs = 0.f;
#pragma unroll
            for (int fn = 0; fn < 4; ++fn)
                rs += tanh_fast(acc[fm][fn][rg] + hb[fn]) * vv[fn];
            rs += __shfl_xor(rs, 1, 16);
            rs += __shfl_xor(rs, 2, 16);
            rs += __shfl_xor(rs, 4, 16);
            rs += __shfl_xor(rs, 8, 16);
            if (l15 == 0)
                s_red[wn * 128 + wm * 64 + fm * 16 + lhi * 4 + rg] = rs;
        }
    __syncthreads();
    if (tid < 128)
        spart[(size_t)nt * 65536 + m0 + tid] = s_red[tid] + s_red[128 + tid];
#undef STAGE
#undef LDA
#undef LDB
#undef MFMA16
}

// ---------- fold nt-partials + mask + softmax ----------
__global__ __launch_bounds__(256) void k_softmax_fold(const float* __restrict__ spart,
                                                      const int* __restrict__ mask,
                                                      float* __restrict__ scores_out,
                                                      float* __restrict__ weights) {
    __shared__ float red[8];
    int b = blockIdx.x, tid = threadIdx.x;
    float vals[8];
    float mx = -INFINITY;
#pragma unroll
    for (int i = 0; i < 8; ++i) {
        int m = b * S_ + tid + i * 256;
        float s = 0.f;
#pragma unroll
        for (int p = 0; p < 8; ++p)
            s += spart[(size_t)p * 65536 + m];
        s = (mask[m] == 1) ? s : NEGV;
        scores_out[m] = s;
        vals[i] = s;
        mx = fmaxf(mx, s);
    }
    for (int off = 32; off; off >>= 1) mx = fmaxf(mx, __shfl_xor(mx, off, 64));
    int wave = tid >> 6;
    if ((tid & 63) == 0) red[wave] = mx;
    __syncthreads();
    mx = fmaxf(fmaxf(red[0], red[1]), fmaxf(red[2], red[3]));
    float sum = 0.f;
#pragma unroll
    for (int i = 0; i < 8; ++i) {
        vals[i] = expf(vals[i] - mx);
        sum += vals[i];
    }
    for (int off = 32; off; off >>= 1) sum += __shfl_xor(sum, off, 64);
    if ((tid & 63) == 0) red[4 + wave] = sum;
    __syncthreads();
    sum = red[4] + red[5] + red[6] + red[7];
    float inv = 1.f / sum;
#pragma unroll
    for (int i = 0; i < 8; ++i)
        weights[b * S_ + tid + i * 256] = vals[i] * inv;
}

// ---------- context partials: read bf16 hi-plane of enc (half traffic) ----------
__global__ __launch_bounds__(256) void k_ctx_partial(const float* __restrict__ weights,
                                                     const unsigned short* __restrict__ ench,
                                                     float* __restrict__ part) {
    int b = blockIdx.x >> 4;
    int chunk = blockIdx.x & 15;
    int tid = threadIdx.x;
    int d0 = tid * 4;
    float4 acc = {0.f, 0.f, 0.f, 0.f};
    int s0 = chunk * 128;
    const float* wrow = weights + b * S_;
    for (int s = s0; s < s0 + 128; ++s) {
        float w = wrow[s];
        if (w != 0.f) {
            ushort4 e = *(const ushort4*)(ench + (size_t)(b * S_ + s) * D_ + d0);
            acc.x += w * bf2f(e.x); acc.y += w * bf2f(e.y);
            acc.z += w * bf2f(e.z); acc.w += w * bf2f(e.w);
        }
    }
    *(float4*)(part + (size_t)blockIdx.x * D_ + d0) = acc;
}

__global__ __launch_bounds__(256) void k_ctx_reduce(const float* __restrict__ part,
                                                    float* __restrict__ ctx) {
    int bd = blockIdx.x * 256 + threadIdx.x;
    int b = bd >> 10, d = bd & 1023;
    float acc = 0.f;
#pragma unroll
    for (int c = 0; c < 16; ++c)
        acc += part[(size_t)(b * 16 + c) * D_ + d];
    ctx[bd] = acc;
}

// ================== fallback path (tiny ws): round-2 kernel ==================
__global__ __launch_bounds__(256, 2) void k_scores_mfma_fb(
    const float* __restrict__ enc,
    const unsigned short* __restrict__ Whi,
    const unsigned short* __restrict__ Wlo,
    const float* __restrict__ hp,
    const float* __restrict__ bias,
    const float* __restrict__ V,
    const int* __restrict__ mask,
    float* __restrict__ scores_out)
{
    __shared__ __align__(16) unsigned short smem[4 * 8192];
    unsigned short* sAhi = smem;
    unsigned short* sAlo = smem + 8192;
    unsigned short* sBhi = smem + 16384;
    unsigned short* sBlo = smem + 24576;

    const int tid  = threadIdx.x;
    const int lane = tid & 63, wid = tid >> 6;
    const int wr = wid >> 1, wc = wid & 1;
    const int l15 = lane & 15, lhi = lane >> 4;
    const int m0 = blockIdx.x * 128;
    const int b  = m0 >> 11;

    float rowsum[4][4] = {};
    float4 pa[8];
    uint4  pbh[4], pbl[4];

#define STAGE_LOAD(NB, KB) do {                                            \
    _Pragma("unroll")                                                      \
    for (int i_ = 0; i_ < 4; ++i_) {                                       \
        int c_ = tid + i_ * 256;                                           \
        int r_ = c_ >> 3, kc_ = c_ & 7;                                    \
        const float* ap_ = enc + (size_t)(m0 + r_) * D_ + (KB) * 64 + kc_ * 8; \
        pa[2 * i_]     = *(const float4*)ap_;                              \
        pa[2 * i_ + 1] = *(const float4*)(ap_ + 4);                        \
        size_t bo_ = (size_t)((NB) * 128 + r_) * D_ + (KB) * 64 + kc_ * 8; \
        pbh[i_] = *(const uint4*)(Whi + bo_);                              \
        pbl[i_] = *(const uint4*)(Wlo + bo_);                              \
    }                                                                      \
} while (0)

#define STAGE_WRITE() do {                                                 \
    _Pragma("unroll")                                                      \
    for (int i_ = 0; i_ < 4; ++i_) {                                       \
        int c_ = tid + i_ * 256;                                           \
        int sc_ = c_ ^ ((c_ >> 3) & 7);                                    \
        float vv_[8] = {pa[2*i_].x, pa[2*i_].y, pa[2*i_].z, pa[2*i_].w,    \
                        pa[2*i_+1].x, pa[2*i_+1].y, pa[2*i_+1].z, pa[2*i_+1].w}; \
        unsigned short th_[8], tl_[8];                                     \
        _Pragma("unroll")                                                  \
        for (int j_ = 0; j_ < 8; ++j_) {                                   \
            th_[j_] = f2bf(vv_[j_]);                                       \
            tl_[j_] = f2bf(vv_[j_] - bf2f(th_[j_]));                       \
        }                                                                  \
        uint4 hw_, lw_;                                                    \
        hw_.x = th_[0] | ((unsigned)th_[1] << 16); hw_.y = th_[2] | ((unsigned)th_[3] << 16); \
        hw_.z = th_[4] | ((unsigned)th_[5] << 16); hw_.w = th_[6] | ((unsigned)th_[7] << 16); \
        lw_.x = tl_[0] | ((unsigned)tl_[1] << 16); lw_.y = tl_[2] | ((unsigned)tl_[3] << 16); \
        lw_.z = tl_[4] | ((unsigned)tl_[5] << 16); lw_.w = tl_[6] | ((unsigned)tl_[7] << 16); \
        *(uint4*)&sAhi[sc_ * 8] = hw_;                                     \
        *(uint4*)&sAlo[sc_ * 8] = lw_;                                     \
        *(uint4*)&sBhi[sc_ * 8] = pbh[i_];                                 \
        *(uint4*)&sBlo[sc_ * 8] = pbl[i_];                                 \
    }                                                                      \
} while (0)

    STAGE_LOAD(0, 0);

    for (int nb = 0; nb < 8; ++nb) {
        f32x4 acc[4][4];
#pragma unroll
        for (int i = 0; i < 4; ++i)
#pragma unroll
            for (int j = 0; j < 4; ++j)
                acc[i][j] = (f32x4){0.f, 0.f, 0.f, 0.f};

        for (int kb = 0; kb < 16; ++kb) {
            __syncthreads();
            STAGE_WRITE();
            __syncthreads();
            int nkb = kb + 1, nnb = nb;
            if (nkb == 16) { nkb = 0; nnb = nb + 1; }
            if (nnb < 8) STAGE_LOAD(nnb, nkb);

#pragma unroll
            for (int ks = 0; ks < 2; ++ks) {
                bf16x8 bh[4], bl[4];
#pragma unroll
                for (int fn = 0; fn < 4; ++fn) {
                    int rB = wc * 64 + fn * 16 + l15;
                    int ch = (rB * 8 + ks * 4 + lhi) ^ (rB & 7);
                    bh[fn] = *(const bf16x8*)&sBhi[ch * 8];
                    bl[fn] = *(const bf16x8*)&sBlo[ch * 8];
                }
#pragma unroll
                for (int fm = 0; fm < 4; ++fm) {
                    int rA = wr * 64 + fm * 16 + l15;
                    int ch = (rA * 8 + ks * 4 + lhi) ^ (rA & 7);
                    bf16x8 ah = *(const bf16x8*)&sAhi[ch * 8];
                    bf16x8 al = *(const bf16x8*)&sAlo[ch * 8];
#pragma unroll
                    for (int fn = 0; fn < 4; ++fn) {
                        acc[fm][fn] = __builtin_amdgcn_mfma_f32_16x16x32_bf16(ah, bh[fn], acc[fm][fn], 0, 0, 0);
                        acc[fm][fn] = __builtin_amdgcn_mfma_f32_16x16x32_bf16(ah, bl[fn], acc[fm][fn], 0, 0, 0);
                        acc[fm][fn] = __builtin_amdgcn_mfma_f32_16x16x32_bf16(al, bh[fn], acc[fm][fn], 0, 0, 0);
                    }
                }
            }
        }

        int n0 = nb * 128;
#pragma unroll
        for (int fn = 0; fn < 4; ++fn) {
            int n = n0 + wc * 64 + fn * 16 + l15;
            float hbv = hp[b * H_ + n] + bias[n];
            float vvv = V[n];
#pragma unroll
            for (int fm = 0; fm < 4; ++fm) {
                f32x4 a = acc[fm][fn];
#pragma unroll
                for (int rg = 0; rg < 4; ++rg)
                    rowsum[fm][rg] += tanh_fast(a[rg] + hbv) * vvv;
            }
        }
    }

    __syncthreads();
    float* s_red = (float*)smem;
#pragma unroll
    for (int fm = 0; fm < 4; ++fm)
#pragma unroll
        for (int rg = 0; rg < 4; ++rg) {
            float v = rowsum[fm][rg];
            v += __shfl_xor(v, 1, 16);
            v += __shfl_xor(v, 2, 16);
            v += __shfl_xor(v, 4, 16);
            v += __shfl_xor(v, 8, 16);
            if (l15 == 0)
                s_red[wc * 128 + wr * 64 + fm * 16 + lhi * 4 + rg] = v;
        }
    __syncthreads();
    if (tid < 128) {
        int m = m0 + tid;
        float sc = s_red[tid] + s_red[128 + tid];
        scores_out[m] = (mask[m] == 1) ? sc : NEGV;
    }
#undef STAGE_LOAD
#undef STAGE_WRITE
}

__global__ __launch_bounds__(256) void k_softmax(const float* __restrict__ scores,
                                                 float* __restrict__ weights) {
    __shared__ float red[8];
    int b = blockIdx.x;
    int tid = threadIdx.x;
    const float* srow = scores + b * S_;
    float vals[8];
    float mx = -INFINITY;
#pragma unroll
    for (int i = 0; i < 8; ++i) {
        vals[i] = srow[tid + i * 256];
        mx = fmaxf(mx, vals[i]);
    }
    for (int off = 32; off; off >>= 1) mx = fmaxf(mx, __shfl_xor(mx, off, 64));
    int wave = tid >> 6;
    if ((tid & 63) == 0) red[wave] = mx;
    __syncthreads();
    mx = fmaxf(fmaxf(red[0], red[1]), fmaxf(red[2], red[3]));
    float sum = 0.f;
#pragma unroll
    for (int i = 0; i < 8; ++i) {
        vals[i] = expf(vals[i] - mx);
        sum += vals[i];
    }
    for (int off = 32; off; off >>= 1) sum += __shfl_xor(sum, off, 64);
    if ((tid & 63) == 0) red[4 + wave] = sum;
    __syncthreads();
    sum = red[4] + red[5] + red[6] + red[7];
    float inv = 1.f / sum;
#pragma unroll
    for (int i = 0; i < 8; ++i)
        weights[b * S_ + tid + i * 256] = vals[i] * inv;
}

__global__ __launch_bounds__(256) void k_ctx_partial_f32(const float* __restrict__ weights,
                                                         const float* __restrict__ enc,
                                                         float* __restrict__ part) {
    int b = blockIdx.x >> 4;
    int chunk = blockIdx.x & 15;
    int tid = threadIdx.x;
    int d0 = tid * 4;
    float4 acc = {0.f, 0.f, 0.f, 0.f};
    int s0 = chunk * 128;
    const float* wrow = weights + b * S_;
    for (int s = s0; s < s0 + 128; ++s) {
        float w = wrow[s];
        if (w != 0.f) {
            float4 e = *(const float4*)(enc + (size_t)(b * S_ + s) * D_ + d0);
            acc.x += w * e.x; acc.y += w * e.y; acc.z += w * e.z; acc.w += w * e.w;
        }
    }
    *(float4*)(part + (size_t)blockIdx.x * D_ + d0) = acc;
}

extern "C" void kernel_launch(void* const* d_in, const int* in_sizes, int n_in,
                              void* d_out, int out_size, void* d_ws, size_t ws_size,
                              hipStream_t stream) {
    const float* ls   = (const float*)d_in[0];
    const float* enc  = (const float*)d_in[1];
    const int*   mask = (const int*)d_in[2];
    const float* W    = (const float*)d_in[3];
    const float* bias = (const float*)d_in[4];
    const float* V    = (const float*)d_in[5];

    float* out     = (float*)d_out;
    float* ctx     = out;
    float* weights = out + 32768;
    float* scores  = out + 98304;

    // fast path: ench(128MB) encl(128MB) Whi(2MB) Wlo(2MB) hp(128KB) spart(2MB) part(2MB)
    const size_t need = 268435456ull + 4194304ull + 131072ull + 2097152ull + 2097152ull;

    if (ws_size >= need) {
        unsigned short* ench = (unsigned short*)d_ws;
        unsigned short* encl = ench + 67108864;
        unsigned short* Whi  = encl + 67108864;
        unsigned short* Wlo  = Whi + 1048576;
        float* hp    = (float*)(Wlo + 1048576);
        float* spart = hp + 32768;              // 8 * 65536 floats
        float* part  = spart + 524288;          // 512 * 1024 floats

        k_splitW_lin<<<512, 256, 0, stream>>>(W, Whi, Wlo);
        k_split_enc<<<32768, 256, 0, stream>>>(enc, ench, encl);
        k_hpart<<<128, 256, 0, stream>>>(ls, W, hp);
        k_scores_128<<<4096, 256, 0, stream>>>(ench, encl, Whi, Wlo, hp, bias, V, spart);
        k_softmax_fold<<<32, 256, 0, stream>>>(spart, mask, scores, weights);
        k_ctx_partial<<<512, 256, 0, stream>>>(weights, ench, part);
        k_ctx_reduce<<<128, 256, 0, stream>>>(part, ctx);
    } else {
        unsigned short* Whi = (unsigned short*)d_ws;
        unsigned short* Wlo = Whi + 1048576;
        float* hp   = (float*)(Wlo + 1048576);
        float* part = hp + 32768;

        k_splitW_lin<<<512, 256, 0, stream>>>(W, Whi, Wlo);
        k_hpart<<<128, 256, 0, stream>>>(ls, W, hp);
        k_scores_mfma_fb<<<512, 256, 0, stream>>>(enc, Whi, Wlo, hp, bias, V, mask, scores);
        k_softmax<<<32, 256, 0, stream>>>(scores, weights);
        k_ctx_partial_f32<<<512, 256, 0, stream>>>(weights, enc, part);
        k_ctx_reduce<<<128, 256, 0, stream>>>(part, ctx);
    }
}

// Round 10
// 400.414 us; speedup vs baseline: 2.2402x; 2.2402x over previous
//
#include <hip/hip_runtime.h>
#include <math.h>
#include <stdint.h>

#define B_ 32
#define S_ 2048
#define D_ 1024
#define H_ 1024
#define NEGV -1000000000000.0f

typedef __attribute__((ext_vector_type(8))) short bf16x8;
typedef __attribute__((ext_vector_type(8))) _Float16 f16x8;
typedef __attribute__((ext_vector_type(4))) float f32x4;

static __device__ __forceinline__ unsigned short f2bf(float x) {
    union { float f; unsigned u; } v; v.f = x;
    unsigned r = v.u + 0x7FFF + ((v.u >> 16) & 1);
    return (unsigned short)(r >> 16);
}
static __device__ __forceinline__ float bf2f(unsigned short h) {
    union { float f; unsigned u; } v; v.u = ((unsigned)h) << 16; return v.f;
}
static __device__ __forceinline__ unsigned short f2h(float x) {
    _Float16 h = (_Float16)x; unsigned short u;
    __builtin_memcpy(&u, &h, 2); return u;
}
static __device__ __forceinline__ float h2f(unsigned short u) {
    _Float16 h; __builtin_memcpy(&h, &u, 2); return (float)h;
}
static __device__ __forceinline__ float tanh_fast(float x) {
    float e = __expf(2.f * x);
    return 1.f - 2.f / (e + 1.f);
}
static __device__ __forceinline__ void gl_lds16(unsigned short* lds, const unsigned short* g) {
    __builtin_amdgcn_global_load_lds(
        (const __attribute__((address_space(1))) unsigned int*)(const void*)g,
        (__attribute__((address_space(3))) unsigned int*)(void*)lds,
        16, 0, 0);
}

// ---------- split We = W[:, D:] into fp16 hi/lo, CHUNK-SWIZZLED storage ----------
// within each 64-elem K-group: stored chunk c' = c ^ (row & 7)  (chunk = 8 elems = 16B)
__global__ __launch_bounds__(256) void k_splitW_f16(const float* __restrict__ W,
                                                    unsigned short* __restrict__ hi,
                                                    unsigned short* __restrict__ lo) {
    int idx = blockIdx.x * 256 + threadIdx.x;   // 131072 chunks
    int h = idx >> 7, kc = idx & 127;
    const float* src = W + (size_t)h * (2 * D_) + D_ + kc * 8;
    float4 a = *(const float4*)src;
    float4 c4 = *(const float4*)(src + 4);
    float v[8] = {a.x, a.y, a.z, a.w, c4.x, c4.y, c4.z, c4.w};
    unsigned short th[8], tl[8];
#pragma unroll
    for (int j = 0; j < 8; ++j) {
        th[j] = f2h(v[j]);
        tl[j] = f2h(v[j] - h2f(th[j]));
    }
    uint4 hw, lw;
    hw.x = th[0] | ((unsigned)th[1] << 16); hw.y = th[2] | ((unsigned)th[3] << 16);
    hw.z = th[4] | ((unsigned)th[5] << 16); hw.w = th[6] | ((unsigned)th[7] << 16);
    lw.x = tl[0] | ((unsigned)tl[1] << 16); lw.y = tl[2] | ((unsigned)tl[3] << 16);
    lw.z = tl[4] | ((unsigned)tl[5] << 16); lw.w = tl[6] | ((unsigned)tl[7] << 16);
    int g = kc >> 3, cc = kc & 7;
    int dst = g * 64 + ((cc ^ (h & 7)) << 3);
    *(uint4*)(hi + (size_t)h * D_ + dst) = hw;
    *(uint4*)(lo + (size_t)h * D_ + dst) = lw;
}

// ---------- enc -> single fp16 plane, CHUNK-SWIZZLED storage ----------
__global__ __launch_bounds__(256) void k_enc_f16(const float* __restrict__ enc,
                                                 unsigned short* __restrict__ out) {
    size_t gid = (size_t)blockIdx.x * 256 + threadIdx.x;   // 8Mi chunks
    size_t row = gid >> 7;
    int kc = (int)(gid & 127);
    const float* src = enc + row * D_ + kc * 8;
    float4 a = *(const float4*)src;
    float4 c4 = *(const float4*)(src + 4);
    float v[8] = {a.x, a.y, a.z, a.w, c4.x, c4.y, c4.z, c4.w};
    unsigned short t[8];
#pragma unroll
    for (int j = 0; j < 8; ++j) t[j] = f2h(v[j]);
    uint4 w;
    w.x = t[0] | ((unsigned)t[1] << 16); w.y = t[2] | ((unsigned)t[3] << 16);
    w.z = t[4] | ((unsigned)t[5] << 16); w.w = t[6] | ((unsigned)t[7] << 16);
    int g = kc >> 3, cc = kc & 7;
    int dst = g * 64 + ((cc ^ ((int)row & 7)) << 3);
    *(uint4*)(out + row * D_ + dst) = w;
}

// ---------- h_part (fp32, exact) ----------
__global__ __launch_bounds__(256) void k_hpart(const float* __restrict__ ls,
                                               const float* __restrict__ W,
                                               float* __restrict__ hp) {
    int bh = blockIdx.x * 256 + threadIdx.x;
    int b = bh >> 10, h = bh & 1023;
    const float* lsr = ls + b * D_;
    const float* wr  = W + (size_t)h * (2 * D_);
    float acc = 0.f;
#pragma unroll 4
    for (int d = 0; d < D_; d += 4) {
        float4 a = *(const float4*)(lsr + d);
        float4 w = *(const float4*)(wr + d);
        acc += a.x * w.x + a.y * w.y + a.z * w.z + a.w * w.w;
    }
    hp[bh] = acc;
}

// ---------- main GEMM: 256x256 tile, BK=64, double-buffered 2-phase (r6 schedule) ----------
// fp16, 2-term W-split: K'' = 2048 = 32 K-tiles: tile t -> gd = t>>1, plane p = t&1
//   A plane: always ench(f16) ; B plane: p ? Wlo : Whi   =>  a*whi + a*wlo
// Sound pipeline (r6): issue all 8 gl_lds for tile t+1 into slot nxt at iteration
// start, compute t from cur, one __syncthreads per iteration.
__global__ __launch_bounds__(512, 2) void k_scores_f16(
    const unsigned short* __restrict__ ench,
    const unsigned short* __restrict__ Whi,  const unsigned short* __restrict__ Wlo,
    const float* __restrict__ hp, const float* __restrict__ bias,
    const float* __restrict__ V, float* __restrict__ spart)
{
    extern __shared__ unsigned short smem[];     // 131072 B: A[2][256][64] | B[2][256][64]
    unsigned short* smemA = smem;                // slots at 0, 16384 shorts
    unsigned short* smemB = smem + 32768;

    const int tid  = threadIdx.x;
    const int lane = tid & 63, wid = tid >> 6;
    const int wm = wid >> 2, wn = wid & 3;       // 2 x 4 waves
    const int l15 = lane & 15, lhi = lane >> 4;

    // XCD-bijective block swizzle (nwg = 1024, 128 per XCD)
    const int bid  = blockIdx.x;
    const int wgid = (bid & 7) * 128 + (bid >> 3);
    const int mt = wgid >> 2, nt = wgid & 3;
    const int m0 = mt * 256;
    const int nt256 = nt * 256;
    const int b = m0 >> 11;

    const size_t aoff = (size_t)(m0 + wid * 16 + (lane >> 3)) * D_ + (lane & 7) * 8;
    const size_t boff = (size_t)(nt256 + wid * 16 + (lane >> 3)) * D_ + (lane & 7) * 8;
    const int ldsw = wid * 1024;

    f32x4 acc[8][4];
#pragma unroll
    for (int i = 0; i < 8; ++i)
#pragma unroll
        for (int j = 0; j < 4; ++j)
            acc[i][j] = (f32x4){0.f, 0.f, 0.f, 0.f};

    // chunk-swizzled ds_read: stored chunk = logical ^ (row&7); row&7 == l15&7
    const int swz = l15 & 7;

#define STAGE_A(SLOT, HALF, KOFS) do {                                              \
    unsigned short* d_ = &smemA[(SLOT) * 16384 + (HALF) * 8192 + ldsw];             \
    const unsigned short* s_ = ench + aoff + (size_t)(HALF) * 131072 + (KOFS);      \
    gl_lds16(d_, s_);                                                               \
    gl_lds16(d_ + 512, s_ + 8192);                                                  \
} while (0)
#define STAGE_B(SLOT, HALF, SRC, KOFS) do {                                         \
    unsigned short* d_ = &smemB[(SLOT) * 16384 + (HALF) * 8192 + ldsw];             \
    const unsigned short* s_ = (SRC) + boff + (size_t)(HALF) * 131072 + (KOFS);     \
    gl_lds16(d_, s_);                                                               \
    gl_lds16(d_ + 512, s_ + 8192);                                                  \
} while (0)

#define LDA(AR, CUR, MH, KS) do {                                                   \
    _Pragma("unroll")                                                               \
    for (int fi_ = 0; fi_ < 4; ++fi_) {                                             \
        int row_ = wm * 128 + (MH) * 64 + fi_ * 16 + l15;                           \
        int ch_  = ((KS) * 4 + lhi) ^ swz;                                          \
        AR[fi_] = *(const f16x8*)&smemA[(CUR) * 16384 + row_ * 64 + ch_ * 8];       \
    }                                                                               \
} while (0)
#define LDB(BR, CUR, KS) do {                                                       \
    _Pragma("unroll")                                                               \
    for (int fi_ = 0; fi_ < 4; ++fi_) {                                             \
        int row_ = wn * 64 + fi_ * 16 + l15;                                        \
        int ch_  = ((KS) * 4 + lhi) ^ swz;                                          \
        BR[fi_] = *(const f16x8*)&smemB[(CUR) * 16384 + row_ * 64 + ch_ * 8];       \
    }                                                                               \
} while (0)
#define MFMA16(AR, BR, MH) do {                                                     \
    __builtin_amdgcn_s_setprio(1);                                                  \
    _Pragma("unroll")                                                               \
    for (int fi_ = 0; fi_ < 4; ++fi_)                                               \
    _Pragma("unroll")                                                               \
        for (int fj_ = 0; fj_ < 4; ++fj_)                                           \
            acc[(MH) * 4 + fi_][fj_] = __builtin_amdgcn_mfma_f32_16x16x32_f16(      \
                AR[fi_], BR[fj_], acc[(MH) * 4 + fi_][fj_], 0, 0, 0);               \
    __builtin_amdgcn_s_setprio(0);                                                  \
} while (0)

    // ---- prologue: stage tile 0 (gd0, B=Whi) into slot 0
    STAGE_B(0, 0, Whi, 0);
    STAGE_B(0, 1, Whi, 0);
    STAGE_A(0, 0, 0);
    STAGE_A(0, 1, 0);
    __syncthreads();                      // vmcnt(0)+lgkmcnt(0)+barrier

    f16x8 a[4], bk[4];
#pragma unroll 1
    for (int t = 0; t < 32; ++t) {
        const int cur = t & 1, nxt = cur ^ 1;

        if (t < 31) {
            const int tn = t + 1;
            const unsigned short* pb = (tn & 1) ? Wlo : Whi;
            const int kofs = (tn >> 1) * 64;
            STAGE_B(nxt, 0, pb, kofs);
            STAGE_B(nxt, 1, pb, kofs);
            STAGE_A(nxt, 0, kofs);
            STAGE_A(nxt, 1, kofs);
        }

#pragma unroll
        for (int ks = 0; ks < 2; ++ks) {
            LDB(bk, cur, ks);
            LDA(a, cur, 0, ks);
            MFMA16(a, bk, 0);
            LDA(a, cur, 1, ks);
            MFMA16(a, bk, 1);
        }

        __syncthreads();   // t+1 loads drained; reads of cur done -> slot reuse safe
    }

    // ---- epilogue: tanh + V-weighted reduce
    float hb[4], vv[4];
#pragma unroll
    for (int fn = 0; fn < 4; ++fn) {
        int h = nt256 + wn * 64 + fn * 16 + l15;
        hb[fn] = hp[b * H_ + h] + bias[h];
        vv[fn] = V[h];
    }
    float* s_red = (float*)smem;
#pragma unroll
    for (int fm = 0; fm < 8; ++fm)
#pragma unroll
        for (int rg = 0; rg < 4; ++rg) {
            float rs = 0.f;
#pragma unroll
            for (int fn = 0; fn < 4; ++fn)
                rs += tanh_fast(acc[fm][fn][rg] + hb[fn]) * vv[fn];
            rs += __shfl_xor(rs, 1, 16);
            rs += __shfl_xor(rs, 2, 16);
            rs += __shfl_xor(rs, 4, 16);
            rs += __shfl_xor(rs, 8, 16);
            if (l15 == 0)
                s_red[wid * 128 + fm * 16 + lhi * 4 + rg] = rs;
        }
    __syncthreads();
    if (tid < 256) {
        int wmr = tid >> 7, rr = tid & 127;
        float v = s_red[(wmr * 4 + 0) * 128 + rr] + s_red[(wmr * 4 + 1) * 128 + rr]
                + s_red[(wmr * 4 + 2) * 128 + rr] + s_red[(wmr * 4 + 3) * 128 + rr];
        spart[(size_t)nt * 65536 + m0 + tid] = v;
    }
#undef STAGE_A
#undef STAGE_B
#undef LDA
#undef LDB
#undef MFMA16
}

// ---------- fold nt-partials + mask + softmax ----------
__global__ __launch_bounds__(256) void k_softmax_fold(const float* __restrict__ spart,
                                                      const int* __restrict__ mask,
                                                      float* __restrict__ scores_out,
                                                      float* __restrict__ weights) {
    __shared__ float red[8];
    int b = blockIdx.x, tid = threadIdx.x;
    float vals[8];
    float mx = -INFINITY;
#pragma unroll
    for (int i = 0; i < 8; ++i) {
        int m = b * S_ + tid + i * 256;
        float s = spart[m] + spart[65536 + m] + spart[131072 + m] + spart[196608 + m];
        s = (mask[m] == 1) ? s : NEGV;
        scores_out[m] = s;
        vals[i] = s;
        mx = fmaxf(mx, s);
    }
    for (int off = 32; off; off >>= 1) mx = fmaxf(mx, __shfl_xor(mx, off, 64));
    int wave = tid >> 6;
    if ((tid & 63) == 0) red[wave] = mx;
    __syncthreads();
    mx = fmaxf(fmaxf(red[0], red[1]), fmaxf(red[2], red[3]));
    float sum = 0.f;
#pragma unroll
    for (int i = 0; i < 8; ++i) {
        vals[i] = expf(vals[i] - mx);
        sum += vals[i];
    }
    for (int off = 32; off; off >>= 1) sum += __shfl_xor(sum, off, 64);
    if ((tid & 63) == 0) red[4 + wave] = sum;
    __syncthreads();
    sum = red[4] + red[5] + red[6] + red[7];
    float inv = 1.f / sum;
#pragma unroll
    for (int i = 0; i < 8; ++i)
        weights[b * S_ + tid + i * 256] = vals[i] * inv;
}

// ---------- context partials: read swizzled fp16 enc plane (half traffic) ----------
__global__ __launch_bounds__(256) void k_ctx_partial_f16(const float* __restrict__ weights,
                                                         const unsigned short* __restrict__ ench,
                                                         float* __restrict__ part) {
    int b = blockIdx.x >> 4;
    int chunk = blockIdx.x & 15;
    int tid = threadIdx.x;
    int d0 = tid * 4;
    int g = d0 >> 6, cc = (d0 >> 3) & 7, o = d0 & 7;
    float4 acc = {0.f, 0.f, 0.f, 0.f};
    int s0 = chunk * 128;
    const float* wrow = weights + b * S_;
    for (int s = s0; s < s0 + 128; ++s) {
        float w = wrow[s];
        if (w != 0.f) {
            int dst = g * 64 + ((cc ^ (s & 7)) << 3) + o;   // (b*S+s)&7 == s&7
            ushort4 e = *(const ushort4*)(ench + (size_t)(b * S_ + s) * D_ + dst);
            acc.x += w * h2f(e.x); acc.y += w * h2f(e.y);
            acc.z += w * h2f(e.z); acc.w += w * h2f(e.w);
        }
    }
    *(float4*)(part + (size_t)blockIdx.x * D_ + d0) = acc;
}

__global__ __launch_bounds__(256) void k_ctx_reduce(const float* __restrict__ part,
                                                    float* __restrict__ ctx) {
    int bd = blockIdx.x * 256 + threadIdx.x;
    int b = bd >> 10, d = bd & 1023;
    float acc = 0.f;
#pragma unroll
    for (int c = 0; c < 16; ++c)
        acc += part[(size_t)(b * 16 + c) * D_ + d];
    ctx[bd] = acc;
}

// ================== fallback path (tiny ws): linear bf16 split + round-2 kernel ==================
__global__ __launch_bounds__(256) void k_splitW_lin(const float* __restrict__ W,
                                                    unsigned short* __restrict__ hi,
                                                    unsigned short* __restrict__ lo) {
    int idx = blockIdx.x * 256 + threadIdx.x;
    int h = idx >> 7, kc = idx & 127;
    const float* src = W + (size_t)h * (2 * D_) + D_ + kc * 8;
    float4 a = *(const float4*)src;
    float4 c = *(const float4*)(src + 4);
    float v[8] = {a.x, a.y, a.z, a.w, c.x, c.y, c.z, c.w};
    unsigned short th[8], tl[8];
#pragma unroll
    for (int j = 0; j < 8; ++j) {
        th[j] = f2bf(v[j]);
        tl[j] = f2bf(v[j] - bf2f(th[j]));
    }
    uint4 hw, lw;
    hw.x = th[0] | ((unsigned)th[1] << 16); hw.y = th[2] | ((unsigned)th[3] << 16);
    hw.z = th[4] | ((unsigned)th[5] << 16); hw.w = th[6] | ((unsigned)th[7] << 16);
    lw.x = tl[0] | ((unsigned)tl[1] << 16); lw.y = tl[2] | ((unsigned)tl[3] << 16);
    lw.z = tl[4] | ((unsigned)tl[5] << 16); lw.w = tl[6] | ((unsigned)tl[7] << 16);
    *(uint4*)(hi + (size_t)h * D_ + kc * 8) = hw;
    *(uint4*)(lo + (size_t)h * D_ + kc * 8) = lw;
}

__global__ __launch_bounds__(256, 2) void k_scores_mfma_fb(
    const float* __restrict__ enc,
    const unsigned short* __restrict__ Whi,
    const unsigned short* __restrict__ Wlo,
    const float* __restrict__ hp,
    const float* __restrict__ bias,
    const float* __restrict__ V,
    const int* __restrict__ mask,
    float* __restrict__ scores_out)
{
    __shared__ __align__(16) unsigned short smem[4 * 8192];
    unsigned short* sAhi = smem;
    unsigned short* sAlo = smem + 8192;
    unsigned short* sBhi = smem + 16384;
    unsigned short* sBlo = smem + 24576;

    const int tid  = threadIdx.x;
    const int lane = tid & 63, wid = tid >> 6;
    const int wr = wid >> 1, wc = wid & 1;
    const int l15 = lane & 15, lhi = lane >> 4;
    const int m0 = blockIdx.x * 128;
    const int b  = m0 >> 11;

    float rowsum[4][4] = {};
    float4 pa[8];
    uint4  pbh[4], pbl[4];

#define STAGE_LOAD(NB, KB) do {                                            \
    _Pragma("unroll")                                                      \
    for (int i_ = 0; i_ < 4; ++i_) {                                       \
        int c_ = tid + i_ * 256;                                           \
        int r_ = c_ >> 3, kc_ = c_ & 7;                                    \
        const float* ap_ = enc + (size_t)(m0 + r_) * D_ + (KB) * 64 + kc_ * 8; \
        pa[2 * i_]     = *(const float4*)ap_;                              \
        pa[2 * i_ + 1] = *(const float4*)(ap_ + 4);                        \
        size_t bo_ = (size_t)((NB) * 128 + r_) * D_ + (KB) * 64 + kc_ * 8; \
        pbh[i_] = *(const uint4*)(Whi + bo_);                              \
        pbl[i_] = *(const uint4*)(Wlo + bo_);                              \
    }                                                                      \
} while (0)

#define STAGE_WRITE() do {                                                 \
    _Pragma("unroll")                                                      \
    for (int i_ = 0; i_ < 4; ++i_) {                                       \
        int c_ = tid + i_ * 256;                                           \
        int sc_ = c_ ^ ((c_ >> 3) & 7);                                    \
        float vv_[8] = {pa[2*i_].x, pa[2*i_].y, pa[2*i_].z, pa[2*i_].w,    \
                        pa[2*i_+1].x, pa[2*i_+1].y, pa[2*i_+1].z, pa[2*i_+1].w}; \
        unsigned short th_[8], tl_[8];                                     \
        _Pragma("unroll")                                                  \
        for (int j_ = 0; j_ < 8; ++j_) {                                   \
            th_[j_] = f2bf(vv_[j_]);                                       \
            tl_[j_] = f2bf(vv_[j_] - bf2f(th_[j_]));                       \
        }                                                                  \
        uint4 hw_, lw_;                                                    \
        hw_.x = th_[0] | ((unsigned)th_[1] << 16); hw_.y = th_[2] | ((unsigned)th_[3] << 16); \
        hw_.z = th_[4] | ((unsigned)th_[5] << 16); hw_.w = th_[6] | ((unsigned)th_[7] << 16); \
        lw_.x = tl_[0] | ((unsigned)tl_[1] << 16); lw_.y = tl_[2] | ((unsigned)tl_[3] << 16); \
        lw_.z = tl_[4] | ((unsigned)tl_[5] << 16); lw_.w = tl_[6] | ((unsigned)tl_[7] << 16); \
        *(uint4*)&sAhi[sc_ * 8] = hw_;                                     \
        *(uint4*)&sAlo[sc_ * 8] = lw_;                                     \
        *(uint4*)&sBhi[sc_ * 8] = pbh[i_];                                 \
        *(uint4*)&sBlo[sc_ * 8] = pbl[i_];                                 \
    }                                                                      \
} while (0)

    STAGE_LOAD(0, 0);

    for (int nb = 0; nb < 8; ++nb) {
        f32x4 acc[4][4];
#pragma unroll
        for (int i = 0; i < 4; ++i)
#pragma unroll
            for (int j = 0; j < 4; ++j)
                acc[i][j] = (f32x4){0.f, 0.f, 0.f, 0.f};

        for (int kb = 0; kb < 16; ++kb) {
            __syncthreads();
            STAGE_WRITE();
            __syncthreads();
            int nkb = kb + 1, nnb = nb;
            if (nkb == 16) { nkb = 0; nnb = nb + 1; }
            if (nnb < 8) STAGE_LOAD(nnb, nkb);

#pragma unroll
            for (int ks = 0; ks < 2; ++ks) {
                bf16x8 bh[4], bl[4];
#pragma unroll
                for (int fn = 0; fn < 4; ++fn) {
                    int rB = wc * 64 + fn * 16 + l15;
                    int ch = (rB * 8 + ks * 4 + lhi) ^ (rB & 7);
                    bh[fn] = *(const bf16x8*)&sBhi[ch * 8];
                    bl[fn] = *(const bf16x8*)&sBlo[ch * 8];
                }
#pragma unroll
                for (int fm = 0; fm < 4; ++fm) {
                    int rA = wr * 64 + fm * 16 + l15;
                    int ch = (rA * 8 + ks * 4 + lhi) ^ (rA & 7);
                    bf16x8 ah = *(const bf16x8*)&sAhi[ch * 8];
                    bf16x8 al = *(const bf16x8*)&sAlo[ch * 8];
#pragma unroll
                    for (int fn = 0; fn < 4; ++fn) {
                        acc[fm][fn] = __builtin_amdgcn_mfma_f32_16x16x32_bf16(ah, bh[fn], acc[fm][fn], 0, 0, 0);
                        acc[fm][fn] = __builtin_amdgcn_mfma_f32_16x16x32_bf16(ah, bl[fn], acc[fm][fn], 0, 0, 0);
                        acc[fm][fn] = __builtin_amdgcn_mfma_f32_16x16x32_bf16(al, bh[fn], acc[fm][fn], 0, 0, 0);
                    }
                }
            }
        }

        int n0 = nb * 128;
#pragma unroll
        for (int fn = 0; fn < 4; ++fn) {
            int n = n0 + wc * 64 + fn * 16 + l15;
            float hbv = hp[b * H_ + n] + bias[n];
            float vvv = V[n];
#pragma unroll
            for (int fm = 0; fm < 4; ++fm) {
                f32x4 a = acc[fm][fn];
#pragma unroll
                for (int rg = 0; rg < 4; ++rg)
                    rowsum[fm][rg] += tanh_fast(a[rg] + hbv) * vvv;
            }
        }
    }

    __syncthreads();
    float* s_red = (float*)smem;
#pragma unroll
    for (int fm = 0; fm < 4; ++fm)
#pragma unroll
        for (int rg = 0; rg < 4; ++rg) {
            float v = rowsum[fm][rg];
            v += __shfl_xor(v, 1, 16);
            v += __shfl_xor(v, 2, 16);
            v += __shfl_xor(v, 4, 16);
            v += __shfl_xor(v, 8, 16);
            if (l15 == 0)
                s_red[wc * 128 + wr * 64 + fm * 16 + lhi * 4 + rg] = v;
        }
    __syncthreads();
    if (tid < 128) {
        int m = m0 + tid;
        float sc = s_red[tid] + s_red[128 + tid];
        scores_out[m] = (mask[m] == 1) ? sc : NEGV;
    }
#undef STAGE_LOAD
#undef STAGE_WRITE
}

__global__ __launch_bounds__(256) void k_softmax(const float* __restrict__ scores,
                                                 float* __restrict__ weights) {
    __shared__ float red[8];
    int b = blockIdx.x;
    int tid = threadIdx.x;
    const float* srow = scores + b * S_;
    float vals[8];
    float mx = -INFINITY;
#pragma unroll
    for (int i = 0; i < 8; ++i) {
        vals[i] = srow[tid + i * 256];
        mx = fmaxf(mx, vals[i]);
    }
    for (int off = 32; off; off >>= 1) mx = fmaxf(mx, __shfl_xor(mx, off, 64));
    int wave = tid >> 6;
    if ((tid & 63) == 0) red[wave] = mx;
    __syncthreads();
    mx = fmaxf(fmaxf(red[0], red[1]), fmaxf(red[2], red[3]));
    float sum = 0.f;
#pragma unroll
    for (int i = 0; i < 8; ++i) {
        vals[i] = expf(vals[i] - mx);
        sum += vals[i];
    }
    for (int off = 32; off; off >>= 1) sum += __shfl_xor(sum, off, 64);
    if ((tid & 63) == 0) red[4 + wave] = sum;
    __syncthreads();
    sum = red[4] + red[5] + red[6] + red[7];
    float inv = 1.f / sum;
#pragma unroll
    for (int i = 0; i < 8; ++i)
        weights[b * S_ + tid + i * 256] = vals[i] * inv;
}

__global__ __launch_bounds__(256) void k_ctx_partial_f32(const float* __restrict__ weights,
                                                         const float* __restrict__ enc,
                                                         float* __restrict__ part) {
    int b = blockIdx.x >> 4;
    int chunk = blockIdx.x & 15;
    int tid = threadIdx.x;
    int d0 = tid * 4;
    float4 acc = {0.f, 0.f, 0.f, 0.f};
    int s0 = chunk * 128;
    const float* wrow = weights + b * S_;
    for (int s = s0; s < s0 + 128; ++s) {
        float w = wrow[s];
        if (w != 0.f) {
            float4 e = *(const float4*)(enc + (size_t)(b * S_ + s) * D_ + d0);
            acc.x += w * e.x; acc.y += w * e.y; acc.z += w * e.z; acc.w += w * e.w;
        }
    }
    *(float4*)(part + (size_t)blockIdx.x * D_ + d0) = acc;
}

extern "C" void kernel_launch(void* const* d_in, const int* in_sizes, int n_in,
                              void* d_out, int out_size, void* d_ws, size_t ws_size,
                              hipStream_t stream) {
    const float* ls   = (const float*)d_in[0];
    const float* enc  = (const float*)d_in[1];
    const int*   mask = (const int*)d_in[2];
    const float* W    = (const float*)d_in[3];
    const float* bias = (const float*)d_in[4];
    const float* V    = (const float*)d_in[5];

    float* out     = (float*)d_out;
    float* ctx     = out;
    float* weights = out + 32768;
    float* scores  = out + 98304;

    // fast path: ench_f16(128MB) Whi(2MB) Wlo(2MB) hp(128KB) spart(1MB) part(2MB)
    const size_t need = 134217728ull + 4194304ull + 131072ull + 1048576ull + 2097152ull;

    if (ws_size >= need) {
        unsigned short* ench = (unsigned short*)d_ws;        // 64Mi halves
        unsigned short* Whi  = ench + 67108864;
        unsigned short* Wlo  = Whi + 1048576;
        float* hp    = (float*)(Wlo + 1048576);
        float* spart = hp + 32768;              // 4 * 65536 floats
        float* part  = spart + 262144;          // 512 * 1024 floats

        hipFuncSetAttribute((const void*)k_scores_f16,
                            hipFuncAttributeMaxDynamicSharedMemorySize, 131072);

        k_splitW_f16<<<512, 256, 0, stream>>>(W, Whi, Wlo);
        k_enc_f16<<<32768, 256, 0, stream>>>(enc, ench);
        k_hpart<<<128, 256, 0, stream>>>(ls, W, hp);
        k_scores_f16<<<1024, 512, 131072, stream>>>(ench, Whi, Wlo, hp, bias, V, spart);
        k_softmax_fold<<<32, 256, 0, stream>>>(spart, mask, scores, weights);
        k_ctx_partial_f16<<<512, 256, 0, stream>>>(weights, ench, part);
        k_ctx_reduce<<<128, 256, 0, stream>>>(part, ctx);
    } else {
        unsigned short* Whi = (unsigned short*)d_ws;
        unsigned short* Wlo = Whi + 1048576;
        float* hp   = (float*)(Wlo + 1048576);
        float* part = hp + 32768;

        k_splitW_lin<<<512, 256, 0, stream>>>(W, Whi, Wlo);
        k_hpart<<<128, 256, 0, stream>>>(ls, W, hp);
        k_scores_mfma_fb<<<512, 256, 0, stream>>>(enc, Whi, Wlo, hp, bias, V, mask, scores);
        k_softmax<<<32, 256, 0, stream>>>(scores, weights);
        k_ctx_partial_f32<<<512, 256, 0, stream>>>(weights, enc, part);
        k_ctx_reduce<<<128, 256, 0, stream>>>(part, ctx);
    }
}

// Round 11
// 299.609 us; speedup vs baseline: 2.9939x; 1.3365x over previous
//
#include <hip/hip_runtime.h>
#include <math.h>
#include <stdint.h>

#define B_ 32
#define S_ 2048
#define D_ 1024
#define H_ 1024
#define NEGV -1000000000000.0f

typedef __attribute__((ext_vector_type(8))) short bf16x8;
typedef __attribute__((ext_vector_type(8))) _Float16 f16x8;
typedef __attribute__((ext_vector_type(4))) float f32x4;

static __device__ __forceinline__ unsigned short f2bf(float x) {
    union { float f; unsigned u; } v; v.f = x;
    unsigned r = v.u + 0x7FFF + ((v.u >> 16) & 1);
    return (unsigned short)(r >> 16);
}
static __device__ __forceinline__ float bf2f(unsigned short h) {
    union { float f; unsigned u; } v; v.u = ((unsigned)h) << 16; return v.f;
}
static __device__ __forceinline__ unsigned short f2h(float x) {
    _Float16 h = (_Float16)x; unsigned short u;
    __builtin_memcpy(&u, &h, 2); return u;
}
static __device__ __forceinline__ float h2f(unsigned short u) {
    _Float16 h; __builtin_memcpy(&h, &u, 2); return (float)h;
}
static __device__ __forceinline__ float tanh_fast(float x) {
    float e = __expf(2.f * x);
    return 1.f - 2.f / (e + 1.f);
}
static __device__ __forceinline__ void gl_lds16(unsigned short* lds, const unsigned short* g) {
    __builtin_amdgcn_global_load_lds(
        (const __attribute__((address_space(1))) unsigned int*)(const void*)g,
        (__attribute__((address_space(3))) unsigned int*)(void*)lds,
        16, 0, 0);
}

// ---------- We = W[:, D:] -> single fp16 plane, CHUNK-SWIZZLED storage ----------
// within each 64-elem K-group: stored chunk c' = c ^ (row & 7)  (chunk = 8 elems = 16B)
__global__ __launch_bounds__(256) void k_W_f16(const float* __restrict__ W,
                                               unsigned short* __restrict__ out) {
    int idx = blockIdx.x * 256 + threadIdx.x;   // 131072 chunks
    int h = idx >> 7, kc = idx & 127;
    const float* src = W + (size_t)h * (2 * D_) + D_ + kc * 8;
    float4 a = *(const float4*)src;
    float4 c4 = *(const float4*)(src + 4);
    float v[8] = {a.x, a.y, a.z, a.w, c4.x, c4.y, c4.z, c4.w};
    unsigned short t[8];
#pragma unroll
    for (int j = 0; j < 8; ++j) t[j] = f2h(v[j]);
    uint4 w;
    w.x = t[0] | ((unsigned)t[1] << 16); w.y = t[2] | ((unsigned)t[3] << 16);
    w.z = t[4] | ((unsigned)t[5] << 16); w.w = t[6] | ((unsigned)t[7] << 16);
    int g = kc >> 3, cc = kc & 7;
    int dst = g * 64 + ((cc ^ (h & 7)) << 3);
    *(uint4*)(out + (size_t)h * D_ + dst) = w;
}

// ---------- enc -> single fp16 plane, CHUNK-SWIZZLED storage ----------
__global__ __launch_bounds__(256) void k_enc_f16(const float* __restrict__ enc,
                                                 unsigned short* __restrict__ out) {
    size_t gid = (size_t)blockIdx.x * 256 + threadIdx.x;   // 8Mi chunks
    size_t row = gid >> 7;
    int kc = (int)(gid & 127);
    const float* src = enc + row * D_ + kc * 8;
    float4 a = *(const float4*)src;
    float4 c4 = *(const float4*)(src + 4);
    float v[8] = {a.x, a.y, a.z, a.w, c4.x, c4.y, c4.z, c4.w};
    unsigned short t[8];
#pragma unroll
    for (int j = 0; j < 8; ++j) t[j] = f2h(v[j]);
    uint4 w;
    w.x = t[0] | ((unsigned)t[1] << 16); w.y = t[2] | ((unsigned)t[3] << 16);
    w.z = t[4] | ((unsigned)t[5] << 16); w.w = t[6] | ((unsigned)t[7] << 16);
    int g = kc >> 3, cc = kc & 7;
    int dst = g * 64 + ((cc ^ ((int)row & 7)) << 3);
    *(uint4*)(out + row * D_ + dst) = w;
}

// ---------- h_part (fp32, exact) ----------
__global__ __launch_bounds__(256) void k_hpart(const float* __restrict__ ls,
                                               const float* __restrict__ W,
                                               float* __restrict__ hp) {
    int bh = blockIdx.x * 256 + threadIdx.x;
    int b = bh >> 10, h = bh & 1023;
    const float* lsr = ls + b * D_;
    const float* wr  = W + (size_t)h * (2 * D_);
    float acc = 0.f;
#pragma unroll 4
    for (int d = 0; d < D_; d += 4) {
        float4 a = *(const float4*)(lsr + d);
        float4 w = *(const float4*)(wr + d);
        acc += a.x * w.x + a.y * w.y + a.z * w.z + a.w * w.w;
    }
    hp[bh] = acc;
}

// ---------- main GEMM: 256x256 tile, BK=64, double-buffered 2-phase (r6 schedule) ----------
// SINGLE fp16 plane both sides: K'' = 1024 = 16 K-tiles, tile t -> kofs = t*64.
// (r10 evidence: absmax identical between 16-bit-effective and 11-bit-effective
// inputs -> output error floor is not input-rounding; W-lo term dropped.)
__global__ __launch_bounds__(512, 2) void k_scores_f16(
    const unsigned short* __restrict__ ench,
    const unsigned short* __restrict__ Wf16,
    const float* __restrict__ hp, const float* __restrict__ bias,
    const float* __restrict__ V, float* __restrict__ spart)
{
    extern __shared__ unsigned short smem[];     // 131072 B: A[2][256][64] | B[2][256][64]
    unsigned short* smemA = smem;                // slots at 0, 16384 shorts
    unsigned short* smemB = smem + 32768;

    const int tid  = threadIdx.x;
    const int lane = tid & 63, wid = tid >> 6;
    const int wm = wid >> 2, wn = wid & 3;       // 2 x 4 waves
    const int l15 = lane & 15, lhi = lane >> 4;

    // XCD-bijective block swizzle (nwg = 1024, 128 per XCD)
    const int bid  = blockIdx.x;
    const int wgid = (bid & 7) * 128 + (bid >> 3);
    const int mt = wgid >> 2, nt = wgid & 3;
    const int m0 = mt * 256;
    const int nt256 = nt * 256;
    const int b = m0 >> 11;

    const size_t aoff = (size_t)(m0 + wid * 16 + (lane >> 3)) * D_ + (lane & 7) * 8;
    const size_t boff = (size_t)(nt256 + wid * 16 + (lane >> 3)) * D_ + (lane & 7) * 8;
    const int ldsw = wid * 1024;

    f32x4 acc[8][4];
#pragma unroll
    for (int i = 0; i < 8; ++i)
#pragma unroll
        for (int j = 0; j < 4; ++j)
            acc[i][j] = (f32x4){0.f, 0.f, 0.f, 0.f};

    // chunk-swizzled ds_read: stored chunk = logical ^ (row&7); row&7 == l15&7
    const int swz = l15 & 7;

#define STAGE_A(SLOT, HALF, KOFS) do {                                              \
    unsigned short* d_ = &smemA[(SLOT) * 16384 + (HALF) * 8192 + ldsw];             \
    const unsigned short* s_ = ench + aoff + (size_t)(HALF) * 131072 + (KOFS);      \
    gl_lds16(d_, s_);                                                               \
    gl_lds16(d_ + 512, s_ + 8192);                                                  \
} while (0)
#define STAGE_B(SLOT, HALF, KOFS) do {                                              \
    unsigned short* d_ = &smemB[(SLOT) * 16384 + (HALF) * 8192 + ldsw];             \
    const unsigned short* s_ = Wf16 + boff + (size_t)(HALF) * 131072 + (KOFS);      \
    gl_lds16(d_, s_);                                                               \
    gl_lds16(d_ + 512, s_ + 8192);                                                  \
} while (0)

#define LDA(AR, CUR, MH, KS) do {                                                   \
    _Pragma("unroll")                                                               \
    for (int fi_ = 0; fi_ < 4; ++fi_) {                                             \
        int row_ = wm * 128 + (MH) * 64 + fi_ * 16 + l15;                           \
        int ch_  = ((KS) * 4 + lhi) ^ swz;                                          \
        AR[fi_] = *(const f16x8*)&smemA[(CUR) * 16384 + row_ * 64 + ch_ * 8];       \
    }                                                                               \
} while (0)
#define LDB(BR, CUR, KS) do {                                                       \
    _Pragma("unroll")                                                               \
    for (int fi_ = 0; fi_ < 4; ++fi_) {                                             \
        int row_ = wn * 64 + fi_ * 16 + l15;                                        \
        int ch_  = ((KS) * 4 + lhi) ^ swz;                                          \
        BR[fi_] = *(const f16x8*)&smemB[(CUR) * 16384 + row_ * 64 + ch_ * 8];       \
    }                                                                               \
} while (0)
#define MFMA16(AR, BR, MH) do {                                                     \
    __builtin_amdgcn_s_setprio(1);                                                  \
    _Pragma("unroll")                                                               \
    for (int fi_ = 0; fi_ < 4; ++fi_)                                               \
    _Pragma("unroll")                                                               \
        for (int fj_ = 0; fj_ < 4; ++fj_)                                           \
            acc[(MH) * 4 + fi_][fj_] = __builtin_amdgcn_mfma_f32_16x16x32_f16(      \
                AR[fi_], BR[fj_], acc[(MH) * 4 + fi_][fj_], 0, 0, 0);               \
    __builtin_amdgcn_s_setprio(0);                                                  \
} while (0)

    // ---- prologue: stage tile 0 into slot 0
    STAGE_B(0, 0, 0);
    STAGE_B(0, 1, 0);
    STAGE_A(0, 0, 0);
    STAGE_A(0, 1, 0);
    __syncthreads();                      // vmcnt(0)+lgkmcnt(0)+barrier

    f16x8 a[4], bk[4];
#pragma unroll 1
    for (int t = 0; t < 16; ++t) {
        const int cur = t & 1, nxt = cur ^ 1;

        if (t < 15) {
            const int kofs = (t + 1) * 64;
            STAGE_B(nxt, 0, kofs);
            STAGE_B(nxt, 1, kofs);
            STAGE_A(nxt, 0, kofs);
            STAGE_A(nxt, 1, kofs);
        }

#pragma unroll
        for (int ks = 0; ks < 2; ++ks) {
            LDB(bk, cur, ks);
            LDA(a, cur, 0, ks);
            MFMA16(a, bk, 0);
            LDA(a, cur, 1, ks);
            MFMA16(a, bk, 1);
        }

        __syncthreads();   // t+1 loads drained; reads of cur done -> slot reuse safe
    }

    // ---- epilogue: tanh + V-weighted reduce
    float hb[4], vv[4];
#pragma unroll
    for (int fn = 0; fn < 4; ++fn) {
        int h = nt256 + wn * 64 + fn * 16 + l15;
        hb[fn] = hp[b * H_ + h] + bias[h];
        vv[fn] = V[h];
    }
    float* s_red = (float*)smem;
#pragma unroll
    for (int fm = 0; fm < 8; ++fm)
#pragma unroll
        for (int rg = 0; rg < 4; ++rg) {
            float rs = 0.f;
#pragma unroll
            for (int fn = 0; fn < 4; ++fn)
                rs += tanh_fast(acc[fm][fn][rg] + hb[fn]) * vv[fn];
            rs += __shfl_xor(rs, 1, 16);
            rs += __shfl_xor(rs, 2, 16);
            rs += __shfl_xor(rs, 4, 16);
            rs += __shfl_xor(rs, 8, 16);
            if (l15 == 0)
                s_red[wid * 128 + fm * 16 + lhi * 4 + rg] = rs;
        }
    __syncthreads();
    if (tid < 256) {
        int wmr = tid >> 7, rr = tid & 127;
        float v = s_red[(wmr * 4 + 0) * 128 + rr] + s_red[(wmr * 4 + 1) * 128 + rr]
                + s_red[(wmr * 4 + 2) * 128 + rr] + s_red[(wmr * 4 + 3) * 128 + rr];
        spart[(size_t)nt * 65536 + m0 + tid] = v;
    }
#undef STAGE_A
#undef STAGE_B
#undef LDA
#undef LDB
#undef MFMA16
}

// ---------- fold nt-partials + mask + softmax ----------
__global__ __launch_bounds__(256) void k_softmax_fold(const float* __restrict__ spart,
                                                      const int* __restrict__ mask,
                                                      float* __restrict__ scores_out,
                                                      float* __restrict__ weights) {
    __shared__ float red[8];
    int b = blockIdx.x, tid = threadIdx.x;
    float vals[8];
    float mx = -INFINITY;
#pragma unroll
    for (int i = 0; i < 8; ++i) {
        int m = b * S_ + tid + i * 256;
        float s = spart[m] + spart[65536 + m] + spart[131072 + m] + spart[196608 + m];
        s = (mask[m] == 1) ? s : NEGV;
        scores_out[m] = s;
        vals[i] = s;
        mx = fmaxf(mx, s);
    }
    for (int off = 32; off; off >>= 1) mx = fmaxf(mx, __shfl_xor(mx, off, 64));
    int wave = tid >> 6;
    if ((tid & 63) == 0) red[wave] = mx;
    __syncthreads();
    mx = fmaxf(fmaxf(red[0], red[1]), fmaxf(red[2], red[3]));
    float sum = 0.f;
#pragma unroll
    for (int i = 0; i < 8; ++i) {
        vals[i] = expf(vals[i] - mx);
        sum += vals[i];
    }
    for (int off = 32; off; off >>= 1) sum += __shfl_xor(sum, off, 64);
    if ((tid & 63) == 0) red[4 + wave] = sum;
    __syncthreads();
    sum = red[4] + red[5] + red[6] + red[7];
    float inv = 1.f / sum;
#pragma unroll
    for (int i = 0; i < 8; ++i)
        weights[b * S_ + tid + i * 256] = vals[i] * inv;
}

// ---------- context partials: read swizzled fp16 enc plane (half traffic) ----------
__global__ __launch_bounds__(256) void k_ctx_partial_f16(const float* __restrict__ weights,
                                                         const unsigned short* __restrict__ ench,
                                                         float* __restrict__ part) {
    int b = blockIdx.x >> 4;
    int chunk = blockIdx.x & 15;
    int tid = threadIdx.x;
    int d0 = tid * 4;
    int g = d0 >> 6, cc = (d0 >> 3) & 7, o = d0 & 7;
    float4 acc = {0.f, 0.f, 0.f, 0.f};
    int s0 = chunk * 128;
    const float* wrow = weights + b * S_;
    for (int s = s0; s < s0 + 128; ++s) {
        float w = wrow[s];
        if (w != 0.f) {
            int dst = g * 64 + ((cc ^ (s & 7)) << 3) + o;   // (b*S+s)&7 == s&7
            ushort4 e = *(const ushort4*)(ench + (size_t)(b * S_ + s) * D_ + dst);
            acc.x += w * h2f(e.x); acc.y += w * h2f(e.y);
            acc.z += w * h2f(e.z); acc.w += w * h2f(e.w);
        }
    }
    *(float4*)(part + (size_t)blockIdx.x * D_ + d0) = acc;
}

__global__ __launch_bounds__(256) void k_ctx_reduce(const float* __restrict__ part,
                                                    float* __restrict__ ctx) {
    int bd = blockIdx.x * 256 + threadIdx.x;
    int b = bd >> 10, d = bd & 1023;
    float acc = 0.f;
#pragma unroll
    for (int c = 0; c < 16; ++c)
        acc += part[(size_t)(b * 16 + c) * D_ + d];
    ctx[bd] = acc;
}

// ================== fallback path (tiny ws): linear bf16 split + round-2 kernel ==================
__global__ __launch_bounds__(256) void k_splitW_lin(const float* __restrict__ W,
                                                    unsigned short* __restrict__ hi,
                                                    unsigned short* __restrict__ lo) {
    int idx = blockIdx.x * 256 + threadIdx.x;
    int h = idx >> 7, kc = idx & 127;
    const float* src = W + (size_t)h * (2 * D_) + D_ + kc * 8;
    float4 a = *(const float4*)src;
    float4 c = *(const float4*)(src + 4);
    float v[8] = {a.x, a.y, a.z, a.w, c.x, c.y, c.z, c.w};
    unsigned short th[8], tl[8];
#pragma unroll
    for (int j = 0; j < 8; ++j) {
        th[j] = f2bf(v[j]);
        tl[j] = f2bf(v[j] - bf2f(th[j]));
    }
    uint4 hw, lw;
    hw.x = th[0] | ((unsigned)th[1] << 16); hw.y = th[2] | ((unsigned)th[3] << 16);
    hw.z = th[4] | ((unsigned)th[5] << 16); hw.w = th[6] | ((unsigned)th[7] << 16);
    lw.x = tl[0] | ((unsigned)tl[1] << 16); lw.y = tl[2] | ((unsigned)tl[3] << 16);
    lw.z = tl[4] | ((unsigned)tl[5] << 16); lw.w = tl[6] | ((unsigned)tl[7] << 16);
    *(uint4*)(hi + (size_t)h * D_ + kc * 8) = hw;
    *(uint4*)(lo + (size_t)h * D_ + kc * 8) = lw;
}

__global__ __launch_bounds__(256, 2) void k_scores_mfma_fb(
    const float* __restrict__ enc,
    const unsigned short* __restrict__ Whi,
    const unsigned short* __restrict__ Wlo,
    const float* __restrict__ hp,
    const float* __restrict__ bias,
    const float* __restrict__ V,
    const int* __restrict__ mask,
    float* __restrict__ scores_out)
{
    __shared__ __align__(16) unsigned short smem[4 * 8192];
    unsigned short* sAhi = smem;
    unsigned short* sAlo = smem + 8192;
    unsigned short* sBhi = smem + 16384;
    unsigned short* sBlo = smem + 24576;

    const int tid  = threadIdx.x;
    const int lane = tid & 63, wid = tid >> 6;
    const int wr = wid >> 1, wc = wid & 1;
    const int l15 = lane & 15, lhi = lane >> 4;
    const int m0 = blockIdx.x * 128;
    const int b  = m0 >> 11;

    float rowsum[4][4] = {};
    float4 pa[8];
    uint4  pbh[4], pbl[4];

#define STAGE_LOAD(NB, KB) do {                                            \
    _Pragma("unroll")                                                      \
    for (int i_ = 0; i_ < 4; ++i_) {                                       \
        int c_ = tid + i_ * 256;                                           \
        int r_ = c_ >> 3, kc_ = c_ & 7;                                    \
        const float* ap_ = enc + (size_t)(m0 + r_) * D_ + (KB) * 64 + kc_ * 8; \
        pa[2 * i_]     = *(const float4*)ap_;                              \
        pa[2 * i_ + 1] = *(const float4*)(ap_ + 4);                        \
        size_t bo_ = (size_t)((NB) * 128 + r_) * D_ + (KB) * 64 + kc_ * 8; \
        pbh[i_] = *(const uint4*)(Whi + bo_);                              \
        pbl[i_] = *(const uint4*)(Wlo + bo_);                              \
    }                                                                      \
} while (0)

#define STAGE_WRITE() do {                                                 \
    _Pragma("unroll")                                                      \
    for (int i_ = 0; i_ < 4; ++i_) {                                       \
        int c_ = tid + i_ * 256;                                           \
        int sc_ = c_ ^ ((c_ >> 3) & 7);                                    \
        float vv_[8] = {pa[2*i_].x, pa[2*i_].y, pa[2*i_].z, pa[2*i_].w,    \
                        pa[2*i_+1].x, pa[2*i_+1].y, pa[2*i_+1].z, pa[2*i_+1].w}; \
        unsigned short th_[8], tl_[8];                                     \
        _Pragma("unroll")                                                  \
        for (int j_ = 0; j_ < 8; ++j_) {                                   \
            th_[j_] = f2bf(vv_[j_]);                                       \
            tl_[j_] = f2bf(vv_[j_] - bf2f(th_[j_]));                       \
        }                                                                  \
        uint4 hw_, lw_;                                                    \
        hw_.x = th_[0] | ((unsigned)th_[1] << 16); hw_.y = th_[2] | ((unsigned)th_[3] << 16); \
        hw_.z = th_[4] | ((unsigned)th_[5] << 16); hw_.w = th_[6] | ((unsigned)th_[7] << 16); \
        lw_.x = tl_[0] | ((unsigned)tl_[1] << 16); lw_.y = tl_[2] | ((unsigned)tl_[3] << 16); \
        lw_.z = tl_[4] | ((unsigned)tl_[5] << 16); lw_.w = tl_[6] | ((unsigned)tl_[7] << 16); \
        *(uint4*)&sAhi[sc_ * 8] = hw_;                                     \
        *(uint4*)&sAlo[sc_ * 8] = lw_;                                     \
        *(uint4*)&sBhi[sc_ * 8] = pbh[i_];                                 \
        *(uint4*)&sBlo[sc_ * 8] = pbl[i_];                                 \
    }                                                                      \
} while (0)

    STAGE_LOAD(0, 0);

    for (int nb = 0; nb < 8; ++nb) {
        f32x4 acc[4][4];
#pragma unroll
        for (int i = 0; i < 4; ++i)
#pragma unroll
            for (int j = 0; j < 4; ++j)
                acc[i][j] = (f32x4){0.f, 0.f, 0.f, 0.f};

        for (int kb = 0; kb < 16; ++kb) {
            __syncthreads();
            STAGE_WRITE();
            __syncthreads();
            int nkb = kb + 1, nnb = nb;
            if (nkb == 16) { nkb = 0; nnb = nb + 1; }
            if (nnb < 8) STAGE_LOAD(nnb, nkb);

#pragma unroll
            for (int ks = 0; ks < 2; ++ks) {
                bf16x8 bh[4], bl[4];
#pragma unroll
                for (int fn = 0; fn < 4; ++fn) {
                    int rB = wc * 64 + fn * 16 + l15;
                    int ch = (rB * 8 + ks * 4 + lhi) ^ (rB & 7);
                    bh[fn] = *(const bf16x8*)&sBhi[ch * 8];
                    bl[fn] = *(const bf16x8*)&sBlo[ch * 8];
                }
#pragma unroll
                for (int fm = 0; fm < 4; ++fm) {
                    int rA = wr * 64 + fm * 16 + l15;
                    int ch = (rA * 8 + ks * 4 + lhi) ^ (rA & 7);
                    bf16x8 ah = *(const bf16x8*)&sAhi[ch * 8];
                    bf16x8 al = *(const bf16x8*)&sAlo[ch * 8];
#pragma unroll
                    for (int fn = 0; fn < 4; ++fn) {
                        acc[fm][fn] = __builtin_amdgcn_mfma_f32_16x16x32_bf16(ah, bh[fn], acc[fm][fn], 0, 0, 0);
                        acc[fm][fn] = __builtin_amdgcn_mfma_f32_16x16x32_bf16(ah, bl[fn], acc[fm][fn], 0, 0, 0);
                        acc[fm][fn] = __builtin_amdgcn_mfma_f32_16x16x32_bf16(al, bh[fn], acc[fm][fn], 0, 0, 0);
                    }
                }
            }
        }

        int n0 = nb * 128;
#pragma unroll
        for (int fn = 0; fn < 4; ++fn) {
            int n = n0 + wc * 64 + fn * 16 + l15;
            float hbv = hp[b * H_ + n] + bias[n];
            float vvv = V[n];
#pragma unroll
            for (int fm = 0; fm < 4; ++fm) {
                f32x4 a = acc[fm][fn];
#pragma unroll
                for (int rg = 0; rg < 4; ++rg)
                    rowsum[fm][rg] += tanh_fast(a[rg] + hbv) * vvv;
            }
        }
    }

    __syncthreads();
    float* s_red = (float*)smem;
#pragma unroll
    for (int fm = 0; fm < 4; ++fm)
#pragma unroll
        for (int rg = 0; rg < 4; ++rg) {
            float v = rowsum[fm][rg];
            v += __shfl_xor(v, 1, 16);
            v += __shfl_xor(v, 2, 16);
            v += __shfl_xor(v, 4, 16);
            v += __shfl_xor(v, 8, 16);
            if (l15 == 0)
                s_red[wc * 128 + wr * 64 + fm * 16 + lhi * 4 + rg] = v;
        }
    __syncthreads();
    if (tid < 128) {
        int m = m0 + tid;
        float sc = s_red[tid] + s_red[128 + tid];
        scores_out[m] = (mask[m] == 1) ? sc : NEGV;
    }
#undef STAGE_LOAD
#undef STAGE_WRITE
}

__global__ __launch_bounds__(256) void k_softmax(const float* __restrict__ scores,
                                                 float* __restrict__ weights) {
    __shared__ float red[8];
    int b = blockIdx.x;
    int tid = threadIdx.x;
    const float* srow = scores + b * S_;
    float vals[8];
    float mx = -INFINITY;
#pragma unroll
    for (int i = 0; i < 8; ++i) {
        vals[i] = srow[tid + i * 256];
        mx = fmaxf(mx, vals[i]);
    }
    for (int off = 32; off; off >>= 1) mx = fmaxf(mx, __shfl_xor(mx, off, 64));
    int wave = tid >> 6;
    if ((tid & 63) == 0) red[wave] = mx;
    __syncthreads();
    mx = fmaxf(fmaxf(red[0], red[1]), fmaxf(red[2], red[3]));
    float sum = 0.f;
#pragma unroll
    for (int i = 0; i < 8; ++i) {
        vals[i] = expf(vals[i] - mx);
        sum += vals[i];
    }
    for (int off = 32; off; off >>= 1) sum += __shfl_xor(sum, off, 64);
    if ((tid & 63) == 0) red[4 + wave] = sum;
    __syncthreads();
    sum = red[4] + red[5] + red[6] + red[7];
    float inv = 1.f / sum;
#pragma unroll
    for (int i = 0; i < 8; ++i)
        weights[b * S_ + tid + i * 256] = vals[i] * inv;
}

__global__ __launch_bounds__(256) void k_ctx_partial_f32(const float* __restrict__ weights,
                                                         const float* __restrict__ enc,
                                                         float* __restrict__ part) {
    int b = blockIdx.x >> 4;
    int chunk = blockIdx.x & 15;
    int tid = threadIdx.x;
    int d0 = tid * 4;
    float4 acc = {0.f, 0.f, 0.f, 0.f};
    int s0 = chunk * 128;
    const float* wrow = weights + b * S_;
    for (int s = s0; s < s0 + 128; ++s) {
        float w = wrow[s];
        if (w != 0.f) {
            float4 e = *(const float4*)(enc + (size_t)(b * S_ + s) * D_ + d0);
            acc.x += w * e.x; acc.y += w * e.y; acc.z += w * e.z; acc.w += w * e.w;
        }
    }
    *(float4*)(part + (size_t)blockIdx.x * D_ + d0) = acc;
}

extern "C" void kernel_launch(void* const* d_in, const int* in_sizes, int n_in,
                              void* d_out, int out_size, void* d_ws, size_t ws_size,
                              hipStream_t stream) {
    const float* ls   = (const float*)d_in[0];
    const float* enc  = (const float*)d_in[1];
    const int*   mask = (const int*)d_in[2];
    const float* W    = (const float*)d_in[3];
    const float* bias = (const float*)d_in[4];
    const float* V    = (const float*)d_in[5];

    float* out     = (float*)d_out;
    float* ctx     = out;
    float* weights = out + 32768;
    float* scores  = out + 98304;

    // fast path: ench_f16(128MB) Wf16(2MB) hp(128KB) spart(1MB) part(2MB)
    const size_t need = 134217728ull + 2097152ull + 131072ull + 1048576ull + 2097152ull;

    if (ws_size >= need) {
        unsigned short* ench = (unsigned short*)d_ws;        // 64Mi halves
        unsigned short* Wf16 = ench + 67108864;              // 1Mi halves
        float* hp    = (float*)(Wf16 + 1048576);
        float* spart = hp + 32768;              // 4 * 65536 floats
        float* part  = spart + 262144;          // 512 * 1024 floats

        hipFuncSetAttribute((const void*)k_scores_f16,
                            hipFuncAttributeMaxDynamicSharedMemorySize, 131072);

        k_W_f16<<<512, 256, 0, stream>>>(W, Wf16);
        k_enc_f16<<<32768, 256, 0, stream>>>(enc, ench);
        k_hpart<<<128, 256, 0, stream>>>(ls, W, hp);
        k_scores_f16<<<1024, 512, 131072, stream>>>(ench, Wf16, hp, bias, V, spart);
        k_softmax_fold<<<32, 256, 0, stream>>>(spart, mask, scores, weights);
        k_ctx_partial_f16<<<512, 256, 0, stream>>>(weights, ench, part);
        k_ctx_reduce<<<128, 256, 0, stream>>>(part, ctx);
    } else {
        unsigned short* Whi = (unsigned short*)d_ws;
        unsigned short* Wlo = Whi + 1048576;
        float* hp   = (float*)(Wlo + 1048576);
        float* part = hp + 32768;

        k_splitW_lin<<<512, 256, 0, stream>>>(W, Whi, Wlo);
        k_hpart<<<128, 256, 0, stream>>>(ls, W, hp);
        k_scores_mfma_fb<<<512, 256, 0, stream>>>(enc, Whi, Wlo, hp, bias, V, mask, scores);
        k_softmax<<<32, 256, 0, stream>>>(scores, weights);
        k_ctx_partial_f32<<<512, 256, 0, stream>>>(weights, enc, part);
        k_ctx_reduce<<<128, 256, 0, stream>>>(part, ctx);
    }
}

// Round 12
// 256.691 us; speedup vs baseline: 3.4945x; 1.1672x over previous
//
#include <hip/hip_runtime.h>
#include <math.h>
#include <stdint.h>

#define B_ 32
#define S_ 2048
#define D_ 1024
#define H_ 1024
#define NEGV -1000000000000.0f

typedef __attribute__((ext_vector_type(8))) short bf16x8;
typedef __attribute__((ext_vector_type(8))) _Float16 f16x8;
typedef __attribute__((ext_vector_type(4))) float f32x4;

static __device__ __forceinline__ unsigned short f2bf(float x) {
    union { float f; unsigned u; } v; v.f = x;
    unsigned r = v.u + 0x7FFF + ((v.u >> 16) & 1);
    return (unsigned short)(r >> 16);
}
static __device__ __forceinline__ float bf2f(unsigned short h) {
    union { float f; unsigned u; } v; v.u = ((unsigned)h) << 16; return v.f;
}
static __device__ __forceinline__ unsigned short f2h(float x) {
    _Float16 h = (_Float16)x; unsigned short u;
    __builtin_memcpy(&u, &h, 2); return u;
}
static __device__ __forceinline__ float h2f(unsigned short u) {
    _Float16 h; __builtin_memcpy(&h, &u, 2); return (float)h;
}
static __device__ __forceinline__ float tanh_fast(float x) {
    float e = __expf(2.f * x);
    return 1.f - 2.f / (e + 1.f);
}
static __device__ __forceinline__ void gl_lds16(unsigned short* lds, const unsigned short* g) {
    __builtin_amdgcn_global_load_lds(
        (const __attribute__((address_space(1))) unsigned int*)(const void*)g,
        (__attribute__((address_space(3))) unsigned int*)(void*)lds,
        16, 0, 0);
}

// ---------- We = W[:, D:] -> single fp16 plane, CHUNK-SWIZZLED storage ----------
// within each 64-elem K-group: stored chunk c' = c ^ (row & 7)  (chunk = 8 elems = 16B)
__global__ __launch_bounds__(256) void k_W_f16(const float* __restrict__ W,
                                               unsigned short* __restrict__ out) {
    int idx = blockIdx.x * 256 + threadIdx.x;   // 131072 chunks
    int h = idx >> 7, kc = idx & 127;
    const float* src = W + (size_t)h * (2 * D_) + D_ + kc * 8;
    float4 a = *(const float4*)src;
    float4 c4 = *(const float4*)(src + 4);
    float v[8] = {a.x, a.y, a.z, a.w, c4.x, c4.y, c4.z, c4.w};
    unsigned short t[8];
#pragma unroll
    for (int j = 0; j < 8; ++j) t[j] = f2h(v[j]);
    uint4 w;
    w.x = t[0] | ((unsigned)t[1] << 16); w.y = t[2] | ((unsigned)t[3] << 16);
    w.z = t[4] | ((unsigned)t[5] << 16); w.w = t[6] | ((unsigned)t[7] << 16);
    int g = kc >> 3, cc = kc & 7;
    int dst = g * 64 + ((cc ^ (h & 7)) << 3);
    *(uint4*)(out + (size_t)h * D_ + dst) = w;
}

// ---------- h_part (fp32, exact) ----------
__global__ __launch_bounds__(256) void k_hpart(const float* __restrict__ ls,
                                               const float* __restrict__ W,
                                               float* __restrict__ hp) {
    int bh = blockIdx.x * 256 + threadIdx.x;
    int b = bh >> 10, h = bh & 1023;
    const float* lsr = ls + b * D_;
    const float* wr  = W + (size_t)h * (2 * D_);
    float acc = 0.f;
#pragma unroll 4
    for (int d = 0; d < D_; d += 4) {
        float4 a = *(const float4*)(lsr + d);
        float4 w = *(const float4*)(wr + d);
        acc += a.x * w.x + a.y * w.y + a.z * w.z + a.w * w.w;
    }
    hp[bh] = acc;
}

// ---------- main GEMM: 256x256 tile, BK=64, 2-phase double-buffer, FUSED A-conversion ----------
// A is read from fp32 enc directly: per iteration, 8 float4 loads for tile t+1 are
// issued BEFORE compute(t) (T14 issue-early); after compute, convert+ds_write_b128
// into slot nxt (compiler's vmcnt lands here, leaving B's newer gl_lds in flight);
// one __syncthreads per iteration (r6-proven sound). B stays gl_lds from the tiny
// pre-converted swizzled Wf16. Eliminates the 384MB enc->fp16 HBM round-trip pass.
__global__ __launch_bounds__(512, 2) void k_scores_fused(
    const float* __restrict__ enc,
    const unsigned short* __restrict__ Wf16,
    const float* __restrict__ hp, const float* __restrict__ bias,
    const float* __restrict__ V, float* __restrict__ spart)
{
    extern __shared__ unsigned short smem[];     // 131072 B: A[2][256][64] | B[2][256][64]
    unsigned short* smemA = smem;                // slots at 0, 16384 shorts
    unsigned short* smemB = smem + 32768;

    const int tid  = threadIdx.x;
    const int lane = tid & 63, wid = tid >> 6;
    const int wm = wid >> 2, wn = wid & 3;       // 2 x 4 waves
    const int l15 = lane & 15, lhi = lane >> 4;

    // XCD-bijective block swizzle (nwg = 1024, 128 per XCD)
    const int bid  = blockIdx.x;
    const int wgid = (bid & 7) * 128 + (bid >> 3);
    const int mt = wgid >> 2, nt = wgid & 3;
    const int m0 = mt * 256;
    const int nt256 = nt * 256;
    const int b = m0 >> 11;

    const size_t boff = (size_t)(nt256 + wid * 16 + (lane >> 3)) * D_ + (lane & 7) * 8;
    const int ldsw = wid * 1024;

    f32x4 acc[8][4];
#pragma unroll
    for (int i = 0; i < 8; ++i)
#pragma unroll
        for (int j = 0; j < 4; ++j)
            acc[i][j] = (f32x4){0.f, 0.f, 0.f, 0.f};

    // chunk-swizzled ds_read: stored chunk = logical ^ (row&7); row&7 == l15&7
    const int swz = l15 & 7;

    // A reg-staging: piece p = tid + s*512 (s=0..3): row = p>>3, pc = p&7
    // 8 consecutive lanes cover one row's 8 chunks -> coalesced 256B/row
    float4 ar0[4], ar1[4];

#define LOAD_A(KOFS) do {                                                           \
    _Pragma("unroll")                                                               \
    for (int s_ = 0; s_ < 4; ++s_) {                                                \
        int p_ = tid + s_ * 512;                                                    \
        int row_ = p_ >> 3, pc_ = p_ & 7;                                           \
        const float* ap_ = enc + (size_t)(m0 + row_) * D_ + (KOFS) + pc_ * 8;       \
        ar0[s_] = *(const float4*)ap_;                                              \
        ar1[s_] = *(const float4*)(ap_ + 4);                                        \
    }                                                                               \
} while (0)
#define WRITE_A(SLOT) do {                                                          \
    _Pragma("unroll")                                                               \
    for (int s_ = 0; s_ < 4; ++s_) {                                                \
        int p_ = tid + s_ * 512;                                                    \
        int row_ = p_ >> 3, pc_ = p_ & 7;                                           \
        float v_[8] = {ar0[s_].x, ar0[s_].y, ar0[s_].z, ar0[s_].w,                  \
                       ar1[s_].x, ar1[s_].y, ar1[s_].z, ar1[s_].w};                 \
        unsigned short t_[8];                                                       \
        _Pragma("unroll")                                                           \
        for (int j_ = 0; j_ < 8; ++j_) t_[j_] = f2h(v_[j_]);                        \
        uint4 w_;                                                                   \
        w_.x = t_[0] | ((unsigned)t_[1] << 16); w_.y = t_[2] | ((unsigned)t_[3] << 16); \
        w_.z = t_[4] | ((unsigned)t_[5] << 16); w_.w = t_[6] | ((unsigned)t_[7] << 16); \
        *(uint4*)&smemA[(SLOT) * 16384 + row_ * 64 + ((pc_ ^ (row_ & 7)) << 3)] = w_; \
    }                                                                               \
} while (0)

#define STAGE_B(SLOT, HALF, KOFS) do {                                              \
    unsigned short* d_ = &smemB[(SLOT) * 16384 + (HALF) * 8192 + ldsw];             \
    const unsigned short* s_ = Wf16 + boff + (size_t)(HALF) * 131072 + (KOFS);      \
    gl_lds16(d_, s_);                                                               \
    gl_lds16(d_ + 512, s_ + 8192);                                                  \
} while (0)

#define LDA(AR, CUR, MH, KS) do {                                                   \
    _Pragma("unroll")                                                               \
    for (int fi_ = 0; fi_ < 4; ++fi_) {                                             \
        int row_ = wm * 128 + (MH) * 64 + fi_ * 16 + l15;                           \
        int ch_  = ((KS) * 4 + lhi) ^ swz;                                          \
        AR[fi_] = *(const f16x8*)&smemA[(CUR) * 16384 + row_ * 64 + ch_ * 8];       \
    }                                                                               \
} while (0)
#define LDB(BR, CUR, KS) do {                                                       \
    _Pragma("unroll")                                                               \
    for (int fi_ = 0; fi_ < 4; ++fi_) {                                             \
        int row_ = wn * 64 + fi_ * 16 + l15;                                        \
        int ch_  = ((KS) * 4 + lhi) ^ swz;                                          \
        BR[fi_] = *(const f16x8*)&smemB[(CUR) * 16384 + row_ * 64 + ch_ * 8];       \
    }                                                                               \
} while (0)
#define MFMA16(AR, BR, MH) do {                                                     \
    __builtin_amdgcn_s_setprio(1);                                                  \
    _Pragma("unroll")                                                               \
    for (int fi_ = 0; fi_ < 4; ++fi_)                                               \
    _Pragma("unroll")                                                               \
        for (int fj_ = 0; fj_ < 4; ++fj_)                                           \
            acc[(MH) * 4 + fi_][fj_] = __builtin_amdgcn_mfma_f32_16x16x32_f16(      \
                AR[fi_], BR[fj_], acc[(MH) * 4 + fi_][fj_], 0, 0, 0);               \
    __builtin_amdgcn_s_setprio(0);                                                  \
} while (0)

    // ---- prologue: stage tile 0 into slot 0
    LOAD_A(0);
    STAGE_B(0, 0, 0);
    STAGE_B(0, 1, 0);
    WRITE_A(0);
    __syncthreads();                      // vmcnt(0)+lgkmcnt(0)+barrier

    f16x8 a[4], bk[4];
#pragma unroll 1
    for (int t = 0; t < 16; ++t) {
        const int cur = t & 1, nxt = cur ^ 1;
        const int kofs = (t + 1) * 64;

        if (t < 15) {
            LOAD_A(kofs);                 // 8 float4 global loads issued early
            STAGE_B(nxt, 0, kofs);        // 4 gl_lds issued after (newer)
            STAGE_B(nxt, 1, kofs);
        }

#pragma unroll
        for (int ks = 0; ks < 2; ++ks) {
            LDB(bk, cur, ks);
            LDA(a, cur, 0, ks);
            MFMA16(a, bk, 0);
            LDA(a, cur, 1, ks);
            MFMA16(a, bk, 1);
        }

        if (t < 15) WRITE_A(nxt);         // vmcnt wait lands here (A only; B still in flight)

        __syncthreads();   // B gl_lds drained + ds_writes visible; cur reads done
    }

    // ---- epilogue: tanh + V-weighted reduce
    float hb[4], vv[4];
#pragma unroll
    for (int fn = 0; fn < 4; ++fn) {
        int h = nt256 + wn * 64 + fn * 16 + l15;
        hb[fn] = hp[b * H_ + h] + bias[h];
        vv[fn] = V[h];
    }
    float* s_red = (float*)smem;
#pragma unroll
    for (int fm = 0; fm < 8; ++fm)
#pragma unroll
        for (int rg = 0; rg < 4; ++rg) {
            float rs = 0.f;
#pragma unroll
            for (int fn = 0; fn < 4; ++fn)
                rs += tanh_fast(acc[fm][fn][rg] + hb[fn]) * vv[fn];
            rs += __shfl_xor(rs, 1, 16);
            rs += __shfl_xor(rs, 2, 16);
            rs += __shfl_xor(rs, 4, 16);
            rs += __shfl_xor(rs, 8, 16);
            if (l15 == 0)
                s_red[wid * 128 + fm * 16 + lhi * 4 + rg] = rs;
        }
    __syncthreads();
    if (tid < 256) {
        int wmr = tid >> 7, rr = tid & 127;
        float v = s_red[(wmr * 4 + 0) * 128 + rr] + s_red[(wmr * 4 + 1) * 128 + rr]
                + s_red[(wmr * 4 + 2) * 128 + rr] + s_red[(wmr * 4 + 3) * 128 + rr];
        spart[(size_t)nt * 65536 + m0 + tid] = v;
    }
#undef LOAD_A
#undef WRITE_A
#undef STAGE_B
#undef LDA
#undef LDB
#undef MFMA16
}

// ---------- fold nt-partials + mask + softmax ----------
__global__ __launch_bounds__(256) void k_softmax_fold(const float* __restrict__ spart,
                                                      const int* __restrict__ mask,
                                                      float* __restrict__ scores_out,
                                                      float* __restrict__ weights) {
    __shared__ float red[8];
    int b = blockIdx.x, tid = threadIdx.x;
    float vals[8];
    float mx = -INFINITY;
#pragma unroll
    for (int i = 0; i < 8; ++i) {
        int m = b * S_ + tid + i * 256;
        float s = spart[m] + spart[65536 + m] + spart[131072 + m] + spart[196608 + m];
        s = (mask[m] == 1) ? s : NEGV;
        scores_out[m] = s;
        vals[i] = s;
        mx = fmaxf(mx, s);
    }
    for (int off = 32; off; off >>= 1) mx = fmaxf(mx, __shfl_xor(mx, off, 64));
    int wave = tid >> 6;
    if ((tid & 63) == 0) red[wave] = mx;
    __syncthreads();
    mx = fmaxf(fmaxf(red[0], red[1]), fmaxf(red[2], red[3]));
    float sum = 0.f;
#pragma unroll
    for (int i = 0; i < 8; ++i) {
        vals[i] = expf(vals[i] - mx);
        sum += vals[i];
    }
    for (int off = 32; off; off >>= 1) sum += __shfl_xor(sum, off, 64);
    if ((tid & 63) == 0) red[4 + wave] = sum;
    __syncthreads();
    sum = red[4] + red[5] + red[6] + red[7];
    float inv = 1.f / sum;
#pragma unroll
    for (int i = 0; i < 8; ++i)
        weights[b * S_ + tid + i * 256] = vals[i] * inv;
}

// ---------- context partials (fp32 enc, skip zero weights) ----------
__global__ __launch_bounds__(256) void k_ctx_partial_f32(const float* __restrict__ weights,
                                                         const float* __restrict__ enc,
                                                         float* __restrict__ part) {
    int b = blockIdx.x >> 4;
    int chunk = blockIdx.x & 15;
    int tid = threadIdx.x;
    int d0 = tid * 4;
    float4 acc = {0.f, 0.f, 0.f, 0.f};
    int s0 = chunk * 128;
    const float* wrow = weights + b * S_;
    for (int s = s0; s < s0 + 128; ++s) {
        float w = wrow[s];
        if (w != 0.f) {
            float4 e = *(const float4*)(enc + (size_t)(b * S_ + s) * D_ + d0);
            acc.x += w * e.x; acc.y += w * e.y; acc.z += w * e.z; acc.w += w * e.w;
        }
    }
    *(float4*)(part + (size_t)blockIdx.x * D_ + d0) = acc;
}

__global__ __launch_bounds__(256) void k_ctx_reduce(const float* __restrict__ part,
                                                    float* __restrict__ ctx) {
    int bd = blockIdx.x * 256 + threadIdx.x;
    int b = bd >> 10, d = bd & 1023;
    float acc = 0.f;
#pragma unroll
    for (int c = 0; c < 16; ++c)
        acc += part[(size_t)(b * 16 + c) * D_ + d];
    ctx[bd] = acc;
}

// ================== fallback path (tiny ws): linear bf16 split + round-2 kernel ==================
__global__ __launch_bounds__(256) void k_splitW_lin(const float* __restrict__ W,
                                                    unsigned short* __restrict__ hi,
                                                    unsigned short* __restrict__ lo) {
    int idx = blockIdx.x * 256 + threadIdx.x;
    int h = idx >> 7, kc = idx & 127;
    const float* src = W + (size_t)h * (2 * D_) + D_ + kc * 8;
    float4 a = *(const float4*)src;
    float4 c = *(const float4*)(src + 4);
    float v[8] = {a.x, a.y, a.z, a.w, c.x, c.y, c.z, c.w};
    unsigned short th[8], tl[8];
#pragma unroll
    for (int j = 0; j < 8; ++j) {
        th[j] = f2bf(v[j]);
        tl[j] = f2bf(v[j] - bf2f(th[j]));
    }
    uint4 hw, lw;
    hw.x = th[0] | ((unsigned)th[1] << 16); hw.y = th[2] | ((unsigned)th[3] << 16);
    hw.z = th[4] | ((unsigned)th[5] << 16); hw.w = th[6] | ((unsigned)th[7] << 16);
    lw.x = tl[0] | ((unsigned)tl[1] << 16); lw.y = tl[2] | ((unsigned)tl[3] << 16);
    lw.z = tl[4] | ((unsigned)tl[5] << 16); lw.w = tl[6] | ((unsigned)tl[7] << 16);
    *(uint4*)(hi + (size_t)h * D_ + kc * 8) = hw;
    *(uint4*)(lo + (size_t)h * D_ + kc * 8) = lw;
}

__global__ __launch_bounds__(256, 2) void k_scores_mfma_fb(
    const float* __restrict__ enc,
    const unsigned short* __restrict__ Whi,
    const unsigned short* __restrict__ Wlo,
    const float* __restrict__ hp,
    const float* __restrict__ bias,
    const float* __restrict__ V,
    const int* __restrict__ mask,
    float* __restrict__ scores_out)
{
    __shared__ __align__(16) unsigned short smem[4 * 8192];
    unsigned short* sAhi = smem;
    unsigned short* sAlo = smem + 8192;
    unsigned short* sBhi = smem + 16384;
    unsigned short* sBlo = smem + 24576;

    const int tid  = threadIdx.x;
    const int lane = tid & 63, wid = tid >> 6;
    const int wr = wid >> 1, wc = wid & 1;
    const int l15 = lane & 15, lhi = lane >> 4;
    const int m0 = blockIdx.x * 128;
    const int b  = m0 >> 11;

    float rowsum[4][4] = {};
    float4 pa[8];
    uint4  pbh[4], pbl[4];

#define STAGE_LOAD(NB, KB) do {                                            \
    _Pragma("unroll")                                                      \
    for (int i_ = 0; i_ < 4; ++i_) {                                       \
        int c_ = tid + i_ * 256;                                           \
        int r_ = c_ >> 3, kc_ = c_ & 7;                                    \
        const float* ap_ = enc + (size_t)(m0 + r_) * D_ + (KB) * 64 + kc_ * 8; \
        pa[2 * i_]     = *(const float4*)ap_;                              \
        pa[2 * i_ + 1] = *(const float4*)(ap_ + 4);                        \
        size_t bo_ = (size_t)((NB) * 128 + r_) * D_ + (KB) * 64 + kc_ * 8; \
        pbh[i_] = *(const uint4*)(Whi + bo_);                              \
        pbl[i_] = *(const uint4*)(Wlo + bo_);                              \
    }                                                                      \
} while (0)

#define STAGE_WRITE() do {                                                 \
    _Pragma("unroll")                                                      \
    for (int i_ = 0; i_ < 4; ++i_) {                                       \
        int c_ = tid + i_ * 256;                                           \
        int sc_ = c_ ^ ((c_ >> 3) & 7);                                    \
        float vv_[8] = {pa[2*i_].x, pa[2*i_].y, pa[2*i_].z, pa[2*i_].w,    \
                        pa[2*i_+1].x, pa[2*i_+1].y, pa[2*i_+1].z, pa[2*i_+1].w}; \
        unsigned short th_[8], tl_[8];                                     \
        _Pragma("unroll")                                                  \
        for (int j_ = 0; j_ < 8; ++j_) {                                   \
            th_[j_] = f2bf(vv_[j_]);                                       \
            tl_[j_] = f2bf(vv_[j_] - bf2f(th_[j_]));                       \
        }                                                                  \
        uint4 hw_, lw_;                                                    \
        hw_.x = th_[0] | ((unsigned)th_[1] << 16); hw_.y = th_[2] | ((unsigned)th_[3] << 16); \
        hw_.z = th_[4] | ((unsigned)th_[5] << 16); hw_.w = th_[6] | ((unsigned)th_[7] << 16); \
        lw_.x = tl_[0] | ((unsigned)tl_[1] << 16); lw_.y = tl_[2] | ((unsigned)tl_[3] << 16); \
        lw_.z = tl_[4] | ((unsigned)tl_[5] << 16); lw_.w = tl_[6] | ((unsigned)tl_[7] << 16); \
        *(uint4*)&sAhi[sc_ * 8] = hw_;                                     \
        *(uint4*)&sAlo[sc_ * 8] = lw_;                                     \
        *(uint4*)&sBhi[sc_ * 8] = pbh[i_];                                 \
        *(uint4*)&sBlo[sc_ * 8] = pbl[i_];                                 \
    }                                                                      \
} while (0)

    STAGE_LOAD(0, 0);

    for (int nb = 0; nb < 8; ++nb) {
        f32x4 acc[4][4];
#pragma unroll
        for (int i = 0; i < 4; ++i)
#pragma unroll
            for (int j = 0; j < 4; ++j)
                acc[i][j] = (f32x4){0.f, 0.f, 0.f, 0.f};

        for (int kb = 0; kb < 16; ++kb) {
            __syncthreads();
            STAGE_WRITE();
            __syncthreads();
            int nkb = kb + 1, nnb = nb;
            if (nkb == 16) { nkb = 0; nnb = nb + 1; }
            if (nnb < 8) STAGE_LOAD(nnb, nkb);

#pragma unroll
            for (int ks = 0; ks < 2; ++ks) {
                bf16x8 bh[4], bl[4];
#pragma unroll
                for (int fn = 0; fn < 4; ++fn) {
                    int rB = wc * 64 + fn * 16 + l15;
                    int ch = (rB * 8 + ks * 4 + lhi) ^ (rB & 7);
                    bh[fn] = *(const bf16x8*)&sBhi[ch * 8];
                    bl[fn] = *(const bf16x8*)&sBlo[ch * 8];
                }
#pragma unroll
                for (int fm = 0; fm < 4; ++fm) {
                    int rA = wr * 64 + fm * 16 + l15;
                    int ch = (rA * 8 + ks * 4 + lhi) ^ (rA & 7);
                    bf16x8 ah = *(const bf16x8*)&sAhi[ch * 8];
                    bf16x8 al = *(const bf16x8*)&sAlo[ch * 8];
#pragma unroll
                    for (int fn = 0; fn < 4; ++fn) {
                        acc[fm][fn] = __builtin_amdgcn_mfma_f32_16x16x32_bf16(ah, bh[fn], acc[fm][fn], 0, 0, 0);
                        acc[fm][fn] = __builtin_amdgcn_mfma_f32_16x16x32_bf16(ah, bl[fn], acc[fm][fn], 0, 0, 0);
                        acc[fm][fn] = __builtin_amdgcn_mfma_f32_16x16x32_bf16(al, bh[fn], acc[fm][fn], 0, 0, 0);
                    }
                }
            }
        }

        int n0 = nb * 128;
#pragma unroll
        for (int fn = 0; fn < 4; ++fn) {
            int n = n0 + wc * 64 + fn * 16 + l15;
            float hbv = hp[b * H_ + n] + bias[n];
            float vvv = V[n];
#pragma unroll
            for (int fm = 0; fm < 4; ++fm) {
                f32x4 a = acc[fm][fn];
#pragma unroll
                for (int rg = 0; rg < 4; ++rg)
                    rowsum[fm][rg] += tanh_fast(a[rg] + hbv) * vvv;
            }
        }
    }

    __syncthreads();
    float* s_red = (float*)smem;
#pragma unroll
    for (int fm = 0; fm < 4; ++fm)
#pragma unroll
        for (int rg = 0; rg < 4; ++rg) {
            float v = rowsum[fm][rg];
            v += __shfl_xor(v, 1, 16);
            v += __shfl_xor(v, 2, 16);
            v += __shfl_xor(v, 4, 16);
            v += __shfl_xor(v, 8, 16);
            if (l15 == 0)
                s_red[wc * 128 + wr * 64 + fm * 16 + lhi * 4 + rg] = v;
        }
    __syncthreads();
    if (tid < 128) {
        int m = m0 + tid;
        float sc = s_red[tid] + s_red[128 + tid];
        scores_out[m] = (mask[m] == 1) ? sc : NEGV;
    }
#undef STAGE_LOAD
#undef STAGE_WRITE
}

__global__ __launch_bounds__(256) void k_softmax(const float* __restrict__ scores,
                                                 float* __restrict__ weights) {
    __shared__ float red[8];
    int b = blockIdx.x;
    int tid = threadIdx.x;
    const float* srow = scores + b * S_;
    float vals[8];
    float mx = -INFINITY;
#pragma unroll
    for (int i = 0; i < 8; ++i) {
        vals[i] = srow[tid + i * 256];
        mx = fmaxf(mx, vals[i]);
    }
    for (int off = 32; off; off >>= 1) mx = fmaxf(mx, __shfl_xor(mx, off, 64));
    int wave = tid >> 6;
    if ((tid & 63) == 0) red[wave] = mx;
    __syncthreads();
    mx = fmaxf(fmaxf(red[0], red[1]), fmaxf(red[2], red[3]));
    float sum = 0.f;
#pragma unroll
    for (int i = 0; i < 8; ++i) {
        vals[i] = expf(vals[i] - mx);
        sum += vals[i];
    }
    for (int off = 32; off; off >>= 1) sum += __shfl_xor(sum, off, 64);
    if ((tid & 63) == 0) red[4 + wave] = sum;
    __syncthreads();
    sum = red[4] + red[5] + red[6] + red[7];
    float inv = 1.f / sum;
#pragma unroll
    for (int i = 0; i < 8; ++i)
        weights[b * S_ + tid + i * 256] = vals[i] * inv;
}

extern "C" void kernel_launch(void* const* d_in, const int* in_sizes, int n_in,
                              void* d_out, int out_size, void* d_ws, size_t ws_size,
                              hipStream_t stream) {
    const float* ls   = (const float*)d_in[0];
    const float* enc  = (const float*)d_in[1];
    const int*   mask = (const int*)d_in[2];
    const float* W    = (const float*)d_in[3];
    const float* bias = (const float*)d_in[4];
    const float* V    = (const float*)d_in[5];

    float* out     = (float*)d_out;
    float* ctx     = out;
    float* weights = out + 32768;
    float* scores  = out + 98304;

    // fast path: Wf16(2MB) hp(128KB) spart(1MB) part(2MB) = ~5.3MB
    const size_t need = 2097152ull + 131072ull + 1048576ull + 2097152ull;

    if (ws_size >= need) {
        unsigned short* Wf16 = (unsigned short*)d_ws;         // 1Mi halves
        float* hp    = (float*)(Wf16 + 1048576);
        float* spart = hp + 32768;              // 4 * 65536 floats
        float* part  = spart + 262144;          // 512 * 1024 floats

        hipFuncSetAttribute((const void*)k_scores_fused,
                            hipFuncAttributeMaxDynamicSharedMemorySize, 131072);

        k_W_f16<<<512, 256, 0, stream>>>(W, Wf16);
        k_hpart<<<128, 256, 0, stream>>>(ls, W, hp);
        k_scores_fused<<<1024, 512, 131072, stream>>>(enc, Wf16, hp, bias, V, spart);
        k_softmax_fold<<<32, 256, 0, stream>>>(spart, mask, scores, weights);
        k_ctx_partial_f32<<<512, 256, 0, stream>>>(weights, enc, part);
        k_ctx_reduce<<<128, 256, 0, stream>>>(part, ctx);
    } else {
        unsigned short* Whi = (unsigned short*)d_ws;
        unsigned short* Wlo = Whi + 1048576;
        float* hp   = (float*)(Wlo + 1048576);
        float* part = hp + 32768;

        k_splitW_lin<<<512, 256, 0, stream>>>(W, Whi, Wlo);
        k_hpart<<<128, 256, 0, stream>>>(ls, W, hp);
        k_scores_mfma_fb<<<512, 256, 0, stream>>>(enc, Whi, Wlo, hp, bias, V, mask, scores);
        k_softmax<<<32, 256, 0, stream>>>(scores, weights);
        k_ctx_partial_f32<<<512, 256, 0, stream>>>(weights, enc, part);
        k_ctx_reduce<<<128, 256, 0, stream>>>(part, ctx);
    }
}